// Round 1
// 282.822 us; speedup vs baseline: 1.0008x; 1.0008x over previous
//
#include <hip/hip_runtime.h>

// GraphSAGE 2-layer inference.
// detect -> prep (x->fp8, W1/W2 -> MFMA-frag bf16) -> bucketed CSR build
//  -> agg1 = A_mean * x_fp8  (16-lane group per node, 4 nodes/wave, 8B loads)
//  -> fused MLP (bf16 MFMA): g = relu(agg1 @ W1T + b1) @ W2T -> fp8 (64B rows = 1 line/edge)
//  -> agg2 = A_mean * g_fp8 + b2 -> log_softmax (16-lane group per node, 4 nodes/wave, 4B loads)
// Round-0 lesson: agg kernels are latency-bound on the per-node dependent chain
// (row_ptr -> csr -> shfl -> gather) with 1 node/wave. Fix: group-owns-node,
// 4 nodes per wave in lockstep -> 4x prologue amortization, 4x loads in flight,
// no cross-group reduction, fully coalesced epilogue stores.

typedef __attribute__((ext_vector_type(8))) short bf16x8;
typedef __attribute__((ext_vector_type(4))) float f32x4;
typedef __attribute__((ext_vector_type(2))) float f32x2;

#define BSHIFT 10
#define BMASK  1023
#define SRCMASK 0x1FFFF
#define TBIN   4096

#if __has_builtin(__builtin_amdgcn_cvt_pk_f32_fp8) && __has_builtin(__builtin_amdgcn_cvt_pk_fp8_f32)
#define HAVE_FP8_CVT 1
#else
#define HAVE_FP8_CVT 0
#endif

__device__ inline ushort f2bf(float f) {
  union { float f; unsigned u; } c; c.f = f;
  unsigned r = (c.u + 0x7fffu + ((c.u >> 16) & 1u)) >> 16;
  return (ushort)r;
}
__device__ inline float bf2f(ushort u) {
  union { unsigned u; float f; } c; c.u = ((unsigned)u) << 16;
  return c.f;
}

#if HAVE_FP8_CVT
template <bool HI>
__device__ inline f32x2 fp8x2f(unsigned w) {
  return __builtin_amdgcn_cvt_pk_f32_fp8((int)w, HI);
}
template <bool HI>
__device__ inline unsigned fp8pack2(unsigned old, float a, float b) {
  return (unsigned)__builtin_amdgcn_cvt_pk_fp8_f32(a, b, (int)old, HI);
}
#else
__device__ inline float fp8tof_1(unsigned b) {
  unsigned e = (b >> 3) & 15u, m = b & 7u;
  float v;
  if (e == 0) v = (float)m * 0x1p-9f;
  else { union { unsigned u; float f; } c; c.u = ((e + 120u) << 23) | (m << 20); v = c.f; }
  return (b & 0x80u) ? -v : v;
}
template <bool HI>
__device__ inline f32x2 fp8x2f(unsigned w) {
  unsigned sh = HI ? 16 : 0;
  f32x2 r;
  r.x = fp8tof_1((w >> sh) & 0xFFu);
  r.y = fp8tof_1((w >> (sh + 8)) & 0xFFu);
  return r;
}
__device__ inline unsigned f2fp8_1(float f) {
  float af = fabsf(f);
  unsigned s = (f < 0.f) ? 0x80u : 0u;
  if (!(af < 448.f)) return s | 0x7Eu;
  if (af < 0x1p-6f) {
    int m = (int)rintf(af * 512.0f);
    if (m >= 8) return s | 0x08u;
    return s | (unsigned)m;
  }
  int e;
  frexpf(af, &e);
  int E = e - 1;
  int q = (int)rintf(ldexpf(af, 3 - E));
  if (q >= 16) { q = 8; E += 1; if (E > 8) return s | 0x7Eu; }
  return s | ((unsigned)(E + 7) << 3) | ((unsigned)q & 7u);
}
template <bool HI>
__device__ inline unsigned fp8pack2(unsigned old, float a, float b) {
  unsigned pair = f2fp8_1(a) | (f2fp8_1(b) << 8);
  return HI ? ((old & 0x0000FFFFu) | (pair << 16)) : ((old & 0xFFFF0000u) | pair);
}
#endif

__global__ void __launch_bounds__(64) k_detect(const int* __restrict__ ei, int* __restrict__ flag) {
  int t = threadIdx.x;
  int v = ei[2 * t + 1];
  unsigned long long m = __ballot(v != 0);
  if (t == 0) *flag = (m == 0ull) ? 1 : 0;
}

// x fp32 -> fp8 e4m3 (thread: 8 values, 32B in -> 8B out)
__global__ void __launch_bounds__(256) k_prep_x(const float4* __restrict__ x4, uint2* __restrict__ xq8, int total8) {
  int i = blockIdx.x * 256 + threadIdx.x;
  if (i >= total8) return;
  float4 v0 = x4[2 * i], v1 = x4[2 * i + 1];
  unsigned w0 = fp8pack2<false>(0u, v0.x, v0.y);
  w0 = fp8pack2<true>(w0, v0.z, v0.w);
  unsigned w1 = fp8pack2<false>(0u, v1.x, v1.y);
  w1 = fp8pack2<true>(w1, v1.z, v1.w);
  xq8[i] = make_uint2(w0, w1);
}

// W1[256][128], W2[64][256] -> bf16 MFMA B-fragment order.
__global__ void __launch_bounds__(256) k_prep_w(const float* __restrict__ W1, const float* __restrict__ W2,
                                                ushort* __restrict__ W1f, ushort* __restrict__ W2f) {
  int idx = blockIdx.x * 256 + threadIdx.x;
  if (idx < 32768) {
    int jt = idx >> 11, rem = idx & 2047;
    int kt = rem >> 9, rem2 = rem & 511;
    int l = rem2 >> 3, e = rem2 & 7;
    int k = kt * 32 + (l >> 4) * 8 + e;
    int j = jt * 16 + (l & 15);
    W1f[idx] = f2bf(W1[j * 128 + k]);
  } else {
    int i2 = idx - 32768;
    if (i2 < 16384) {
      int ot = i2 >> 12, rem = i2 & 4095;
      int kt = rem >> 9;
      int l = (rem >> 3) & 63, e = rem & 7;
      int k = kt * 32 + (l >> 4) * 8 + e;
      int o = ot * 16 + (l & 15);
      W2f[i2] = f2bf(W2[o * 256 + k]);
    }
  }
}

__global__ void __launch_bounds__(256) k_bhist(const int* __restrict__ ei, const int* __restrict__ flag,
                                               int* __restrict__ bcnt, int E, int NB) {
  __shared__ int h[128];
  int t = threadIdx.x;
  if (t < 128) h[t] = 0;
  __syncthreads();
  bool f64 = (*flag != 0);
  int stride = gridDim.x * 256;
  for (int e = blockIdx.x * 256 + t; e < E; e += stride) {
    int d;
    if (f64) d = (int)((const long long*)ei)[(size_t)E + e];
    else     d = ei[(size_t)E + e];
    atomicAdd(&h[d >> BSHIFT], 1);
  }
  __syncthreads();
  if (t < NB && h[t]) atomicAdd(&bcnt[t], h[t]);
}

__global__ void __launch_bounds__(128) k_bscan(const int* __restrict__ bcnt, int* __restrict__ bbase,
                                               int* __restrict__ bcur, int* __restrict__ row_ptr,
                                               int NB, int N, int E) {
  __shared__ int s[128];
  int t = threadIdx.x;
  int v = (t < NB) ? bcnt[t] : 0;
  s[t] = v;
  __syncthreads();
  for (int o = 1; o < 128; o <<= 1) {
    int u = (t >= o) ? s[t - o] : 0;
    __syncthreads();
    s[t] += u;
    __syncthreads();
  }
  if (t < NB) {
    int base = s[t] - v;
    bbase[t] = base;
    bcur[t] = base;
  }
  if (t == 0) {
    bbase[NB] = E;
    row_ptr[N] = E;
  }
}

__global__ void __launch_bounds__(256) k_bin(const int* __restrict__ ei, const int* __restrict__ flag,
                                             int* __restrict__ bcur, int* __restrict__ gpair, int E, int NB) {
  __shared__ int hist[128], base[128], segb[128], cur[128], scanb[128];
  __shared__ int ent[TBIN];
  __shared__ int gdx[TBIN];
  int t = threadIdx.x;
  int e0 = blockIdx.x * TBIN;
  int cnt = E - e0; if (cnt > TBIN) cnt = TBIN;
  if (t < 128) hist[t] = 0;
  __syncthreads();
  bool f64 = (*flag != 0);
  int ment[16], mbk[16];
#pragma unroll
  for (int i = 0; i < 16; ++i) {
    int idx = t + i * 256;
    mbk[i] = -1;
    if (idx < cnt) {
      int e = e0 + idx;
      int s, d;
      if (f64) {
        const long long* p = (const long long*)ei;
        s = (int)p[e];
        d = (int)p[(size_t)E + e];
      } else {
        s = ei[e];
        d = ei[(size_t)E + e];
      }
      int b = d >> BSHIFT;
      mbk[i] = b;
      ment[i] = ((d & BMASK) << 17) | s;
      atomicAdd(&hist[b], 1);
    }
  }
  __syncthreads();
  if (t < 128) scanb[t] = hist[t];
  __syncthreads();
  for (int o = 1; o < 128; o <<= 1) {
    int u = 0;
    if (t < 128 && t >= o) u = scanb[t - o];
    __syncthreads();
    if (t < 128) scanb[t] += u;
    __syncthreads();
  }
  if (t < 128) {
    int b0 = scanb[t] - hist[t];
    base[t] = b0;
    cur[t] = b0;
    segb[t] = (t < NB && hist[t] > 0) ? atomicAdd(&bcur[t], hist[t]) : 0;
  }
  __syncthreads();
#pragma unroll
  for (int i = 0; i < 16; ++i) {
    int b = mbk[i];
    if (b >= 0) {
      int pos = atomicAdd(&cur[b], 1);
      ent[pos] = ment[i];
      gdx[pos] = segb[b] + (pos - base[b]);
    }
  }
  __syncthreads();
  for (int i = t; i < cnt; i += 256) gpair[gdx[i]] = ent[i];
}

__global__ void __launch_bounds__(1024) k_bcsr(const int* __restrict__ gpair, const int* __restrict__ bbase,
                                               int* __restrict__ row_ptr, float* __restrict__ inv_deg,
                                               int* __restrict__ csr, int N) {
  __shared__ int hist[1024], pre[1024], cur[1024];
  int b = blockIdx.x, t = threadIdx.x;
  int start = bbase[b], end = bbase[b + 1];
  hist[t] = 0;
  __syncthreads();
  for (int i = start + t; i < end; i += 1024) {
    int e = gpair[i];
    atomicAdd(&hist[e >> 17], 1);
  }
  __syncthreads();
  pre[t] = hist[t];
  __syncthreads();
  for (int o = 1; o < 1024; o <<= 1) {
    int u = (t >= o) ? pre[t - o] : 0;
    __syncthreads();
    pre[t] += u;
    __syncthreads();
  }
  int gbase = start + pre[t] - hist[t];
  int n = (b << BSHIFT) + t;
  if (n < N) {
    row_ptr[n] = gbase;
    inv_deg[n] = 1.0f / (float)(hist[t] > 0 ? hist[t] : 1);
  }
  cur[t] = gbase;
  __syncthreads();
  for (int i = start + t; i < end; i += 1024) {
    int e = gpair[i];
    int pos = atomicAdd(&cur[e >> 17], 1);
    csr[pos] = e & SRCMASK;
  }
}

// agg1: 16-lane group per node, 4 nodes per wave in lockstep.
// Lane covers 8 features (8B fp8 dwordx2 at xq[row*128 + p*8]).
// Group owns its node: no cross-group reduction; row_ptr/csr loads amortized
// over 4 nodes; up to 16 gathers in flight per wave per round.
__global__ void __launch_bounds__(256) k_agg1(const unsigned char* __restrict__ xq, const int* __restrict__ csr,
                                              const int* __restrict__ row_ptr, const float* __restrict__ inv_deg,
                                              ushort* __restrict__ agg1b, int N) {
  const int lane = threadIdx.x & 63;
  const int g = lane >> 4, p = lane & 15;
  const int n0 = (blockIdx.x * 4 + (threadIdx.x >> 6)) * 4;
  if (n0 >= N) return;
  const int n = n0 + g;
  int rpidx = n0 + (lane < 4 ? lane : 4);
  if (rpidx > N) rpidx = N;
  const int rv = row_ptr[rpidx];
  const int s = __shfl(rv, g);
  const int cnt = __shfl(rv, g + 1) - s;
  const float inv = inv_deg[n < N ? n : 0];
  int maxc = cnt;
  maxc = max(maxc, __shfl_xor(maxc, 16));
  maxc = max(maxc, __shfl_xor(maxc, 32));

  f32x2 a0 = (f32x2)(0.f), a1 = (f32x2)(0.f), a2 = (f32x2)(0.f), a3 = (f32x2)(0.f);
  for (int base = 0; base < maxc; base += 16) {
    // stage up to 16 edge indices for this group (clamped -> always a valid address)
    int li = base + p, cm = cnt - 1;
    if (li > cm) li = cm;
    if (li < 0) li = 0;
    int ci = 0;
    if (cnt > 0) ci = csr[s + li];
#pragma unroll
    for (int u = 0; u < 8; ++u) {
      int idx = __shfl(ci, (lane & 48) + u);
      uint2 wv = *(const uint2*)(xq + (size_t)idx * 128 + p * 8);
      if (base + u >= cnt) { wv.x = 0u; wv.y = 0u; }
      a0 += fp8x2f<false>(wv.x); a1 += fp8x2f<true>(wv.x);
      a2 += fp8x2f<false>(wv.y); a3 += fp8x2f<true>(wv.y);
    }
    if (base + 8 < maxc) {
#pragma unroll
      for (int u = 8; u < 16; ++u) {
        int idx = __shfl(ci, (lane & 48) + u);
        uint2 wv = *(const uint2*)(xq + (size_t)idx * 128 + p * 8);
        if (base + u >= cnt) { wv.x = 0u; wv.y = 0u; }
        a0 += fp8x2f<false>(wv.x); a1 += fp8x2f<true>(wv.x);
        a2 += fp8x2f<false>(wv.y); a3 += fp8x2f<true>(wv.y);
      }
    }
  }
  if (n < N) {
    bf16x8 o;
    o[0] = (short)f2bf(a0.x * inv); o[1] = (short)f2bf(a0.y * inv);
    o[2] = (short)f2bf(a1.x * inv); o[3] = (short)f2bf(a1.y * inv);
    o[4] = (short)f2bf(a2.x * inv); o[5] = (short)f2bf(a2.y * inv);
    o[6] = (short)f2bf(a3.x * inv); o[7] = (short)f2bf(a3.y * inv);
    *(bf16x8*)(agg1b + (size_t)n * 128 + p * 8) = o;
  }
}

// Fused MFMA MLP: g = relu(agg1 @ W1T + b1) @ W2T, bf16 in, fp8 out, fp32 accum.
__global__ void __launch_bounds__(256) k_mlp(const ushort* __restrict__ agg1b, const bf16x8* __restrict__ w1f,
                                             const float* __restrict__ b1, const bf16x8* __restrict__ w2f,
                                             unsigned char* __restrict__ gq, int N) {
  __shared__ __align__(16) ushort sm[16896];
  ushort* aT = sm;   // phase1: [64][136]
  ushort* hT = sm;   // phase2: [64][264]
  const int t = threadIdx.x;
  const int n0 = blockIdx.x * 64;

#pragma unroll
  for (int i = 0; i < 4; ++i) {
    int idx = i * 256 + t;
    int row = idx >> 4, c8 = idx & 15;
    int rr = n0 + row; if (rr >= N) rr = N - 1;
    bf16x8 v = *(const bf16x8*)(agg1b + (size_t)rr * 128 + c8 * 8);
    *(bf16x8*)(aT + row * 136 + c8 * 8) = v;
  }
  __syncthreads();

  const int w = t >> 6, l = t & 63;
  const int lm = l & 15, lq = l >> 4;

  f32x4 acc[4][4];
#pragma unroll
  for (int mt = 0; mt < 4; ++mt)
#pragma unroll
    for (int nt = 0; nt < 4; ++nt) acc[mt][nt] = (f32x4)(0.f);

#pragma unroll
  for (int kt = 0; kt < 4; ++kt) {
    bf16x8 b[4], a[4];
#pragma unroll
    for (int nt = 0; nt < 4; ++nt)
      b[nt] = w1f[((w * 4 + nt) * 4 + kt) * 64 + l];
#pragma unroll
    for (int mt = 0; mt < 4; ++mt)
      a[mt] = *(const bf16x8*)(aT + (mt * 16 + lm) * 136 + kt * 32 + lq * 8);
#pragma unroll
    for (int mt = 0; mt < 4; ++mt)
#pragma unroll
      for (int nt = 0; nt < 4; ++nt)
        acc[mt][nt] = __builtin_amdgcn_mfma_f32_16x16x32_bf16(a[mt], b[nt], acc[mt][nt], 0, 0, 0);
  }
  __syncthreads();

#pragma unroll
  for (int nt = 0; nt < 4; ++nt) {
    int col = w * 64 + nt * 16 + lm;
    float bb = b1[col];
#pragma unroll
    for (int mt = 0; mt < 4; ++mt)
#pragma unroll
      for (int r = 0; r < 4; ++r) {
        int row = mt * 16 + lq * 4 + r;
        float hv = acc[mt][nt][r] + bb;
        hT[row * 264 + col] = f2bf(fmaxf(hv, 0.f));
      }
  }
  __syncthreads();

  f32x4 acc2[4];
#pragma unroll
  for (int ot = 0; ot < 4; ++ot) acc2[ot] = (f32x4)(0.f);
#pragma unroll
  for (int kt = 0; kt < 8; ++kt) {
    bf16x8 a2 = *(const bf16x8*)(hT + (w * 16 + lm) * 264 + kt * 32 + lq * 8);
#pragma unroll
    for (int ot = 0; ot < 4; ++ot) {
      bf16x8 bf = w2f[(ot * 8 + kt) * 64 + l];
      acc2[ot] = __builtin_amdgcn_mfma_f32_16x16x32_bf16(a2, bf, acc2[ot], 0, 0, 0);
    }
  }
  // write g in fp8 e4m3
#pragma unroll
  for (int ot = 0; ot < 4; ++ot)
#pragma unroll
    for (int r = 0; r < 4; ++r) {
      int row = n0 + w * 16 + lq * 4 + r;
      if (row < N) {
        unsigned pw = fp8pack2<false>(0u, acc2[ot][r], acc2[ot][r]);
        gq[(size_t)row * 64 + ot * 16 + lm] = (unsigned char)(pw & 0xFFu);
      }
    }
}

// agg2 + b2 + log_softmax. 16-lane group per node, 4 nodes per wave.
// Lane covers 4 features (4B fp8 dword at gq[row*64 + p*4]).
// Softmax is group-local (xor 1/2/4/8 stays inside the 16 lanes);
// all 16 lanes store float4 -> 64 lanes x 16B = 4 full output rows per wave.
__global__ void __launch_bounds__(256) k_agg2(const unsigned char* __restrict__ gq, const int* __restrict__ csr,
                                              const int* __restrict__ row_ptr, const float* __restrict__ inv_deg,
                                              const float* __restrict__ b2, float* __restrict__ out, int N) {
  const int lane = threadIdx.x & 63;
  const int g = lane >> 4, p = lane & 15;
  const int n0 = (blockIdx.x * 4 + (threadIdx.x >> 6)) * 4;
  if (n0 >= N) return;
  const int n = n0 + g;
  int rpidx = n0 + (lane < 4 ? lane : 4);
  if (rpidx > N) rpidx = N;
  const int rv = row_ptr[rpidx];
  const int s = __shfl(rv, g);
  const int cnt = __shfl(rv, g + 1) - s;
  const float inv = inv_deg[n < N ? n : 0];
  const float4 bv = *(const float4*)(b2 + p * 4);
  int maxc = cnt;
  maxc = max(maxc, __shfl_xor(maxc, 16));
  maxc = max(maxc, __shfl_xor(maxc, 32));

  f32x2 a0 = (f32x2)(0.f), a1 = (f32x2)(0.f);
  for (int base = 0; base < maxc; base += 16) {
    int li = base + p, cm = cnt - 1;
    if (li > cm) li = cm;
    if (li < 0) li = 0;
    int ci = 0;
    if (cnt > 0) ci = csr[s + li];
#pragma unroll
    for (int u = 0; u < 8; ++u) {
      int idx = __shfl(ci, (lane & 48) + u);
      unsigned wv = *(const unsigned*)(gq + (size_t)idx * 64 + p * 4);
      if (base + u >= cnt) wv = 0u;
      a0 += fp8x2f<false>(wv); a1 += fp8x2f<true>(wv);
    }
    if (base + 8 < maxc) {
#pragma unroll
      for (int u = 8; u < 16; ++u) {
        int idx = __shfl(ci, (lane & 48) + u);
        unsigned wv = *(const unsigned*)(gq + (size_t)idx * 64 + p * 4);
        if (base + u >= cnt) wv = 0u;
        a0 += fp8x2f<false>(wv); a1 += fp8x2f<true>(wv);
      }
    }
  }
  float vx = a0.x * inv + bv.x;
  float vy = a0.y * inv + bv.y;
  float vz = a1.x * inv + bv.z;
  float vw = a1.y * inv + bv.w;
  float mx = fmaxf(fmaxf(vx, vy), fmaxf(vz, vw));
#pragma unroll
  for (int off = 1; off <= 8; off <<= 1) mx = fmaxf(mx, __shfl_xor(mx, off));
  float se = expf(vx - mx) + expf(vy - mx) + expf(vz - mx) + expf(vw - mx);
#pragma unroll
  for (int off = 1; off <= 8; off <<= 1) se += __shfl_xor(se, off);
  float lse = mx + logf(se);
  if (n < N) {
    float4 o;
    o.x = vx - lse; o.y = vy - lse; o.z = vz - lse; o.w = vw - lse;
    *(float4*)(out + (size_t)n * 64 + p * 4) = o;
  }
}

extern "C" void kernel_launch(void* const* d_in, const int* in_sizes, int n_in,
                              void* d_out, int out_size, void* d_ws, size_t ws_size,
                              hipStream_t stream) {
  const float* x  = (const float*)d_in[0];
  const int*   ei = (const int*)d_in[1];
  const float* W1 = (const float*)d_in[2];
  const float* b1 = (const float*)d_in[3];
  const float* W2 = (const float*)d_in[4];
  const float* b2 = (const float*)d_in[5];
  float* out = (float*)d_out;
  const int N = in_sizes[0] / 128;  // 100000
  const int E = in_sizes[1] / 2;    // 1600000
  const int NB = (N + BMASK) >> BSHIFT;  // 98

  char* base = (char*)d_ws;
  size_t off = 0;
  auto alloc = [&](size_t bytes) -> char* {
    char* p = base + off;
    off += (bytes + 255) & ~(size_t)255;
    return p;
  };
  int*    flag    = (int*)alloc(4);
  int*    bcnt    = (int*)alloc((size_t)NB * 4);
  int*    bbase   = (int*)alloc((size_t)(NB + 1) * 4);
  int*    bcur    = (int*)alloc((size_t)NB * 4);
  int*    gpair   = (int*)alloc((size_t)E * 4);
  int*    row_ptr = (int*)alloc((size_t)(N + 1) * 4);
  float*  inv_deg = (float*)alloc((size_t)N * 4);
  int*    csr     = (int*)alloc((size_t)E * 4);
  unsigned char* xq = (unsigned char*)alloc((size_t)N * 128);
  ushort* W1f     = (ushort*)alloc((size_t)32768 * 2);
  ushort* W2f     = (ushort*)alloc((size_t)16384 * 2);
  ushort* agg1b   = (ushort*)alloc((size_t)N * 128 * 2);
  unsigned char* gq = (unsigned char*)alloc((size_t)N * 64);
  (void)ws_size; (void)n_in; (void)out_size;

  hipMemsetAsync(bcnt, 0, (size_t)NB * 4, stream);
  k_detect<<<1, 64, 0, stream>>>(ei, flag);
  k_prep_x<<<(N * 16 + 255) / 256, 256, 0, stream>>>((const float4*)x, (uint2*)xq, N * 16);
  k_prep_w<<<192, 256, 0, stream>>>(W1, W2, W1f, W2f);
  k_bhist<<<512, 256, 0, stream>>>(ei, flag, bcnt, E, NB);
  k_bscan<<<1, 128, 0, stream>>>(bcnt, bbase, bcur, row_ptr, NB, N, E);
  k_bin<<<(E + TBIN - 1) / TBIN, 256, 0, stream>>>(ei, flag, bcur, gpair, E, NB);
  k_bcsr<<<NB, 1024, 0, stream>>>(gpair, bbase, row_ptr, inv_deg, csr, N);
  k_agg1<<<(N + 15) / 16, 256, 0, stream>>>(xq, csr, row_ptr, inv_deg, agg1b, N);
  k_mlp<<<(N + 63) / 64, 256, 0, stream>>>(agg1b, (const bf16x8*)W1f, b1, (const bf16x8*)W2f, gq, N);
  k_agg2<<<(N + 15) / 16, 256, 0, stream>>>(gq, csr, row_ptr, inv_deg, b2, out, N);
}

// Round 4
// 272.255 us; speedup vs baseline: 1.0396x; 1.0388x over previous
//
#include <hip/hip_runtime.h>

// GraphSAGE 2-layer inference.
// detect(+zero pad rows) -> prep (x->fp8, W1/W2 -> MFMA-frag bf16) -> bucketed CSR build
//  -> agg1 = A_mean * x_fp8  (8 lanes/edge x 16B, 2 edges/group-step, persistent waves)
//  -> fused MLP (bf16 MFMA): g = relu(agg1 @ W1T + b1) @ W2T -> fp8
//  -> agg2 = A_mean * g_fp8 + b2 -> log_softmax (4 lanes/edge x 16B, 4 edges/group-step)
// Round-1 lesson: agg kernels insensitive to VALU halving AND to gather-byte doubling
// -> cut per-edge instruction overhead (zero-row padding kills tail cndmasks; 32-bit
// saddr addressing; wider 16B loads = fewer shfl/addr per edge) + persistent waves.

typedef __attribute__((ext_vector_type(8))) short bf16x8;
typedef __attribute__((ext_vector_type(4))) float f32x4;
typedef __attribute__((ext_vector_type(2))) float f32x2;

#define BSHIFT 10
#define BMASK  1023
#define SRCMASK 0x1FFFF
#define TBIN   4096

#if __has_builtin(__builtin_amdgcn_cvt_pk_f32_fp8) && __has_builtin(__builtin_amdgcn_cvt_pk_fp8_f32)
#define HAVE_FP8_CVT 1
#else
#define HAVE_FP8_CVT 0
#endif

__device__ inline ushort f2bf(float f) {
  union { float f; unsigned u; } c; c.f = f;
  unsigned r = (c.u + 0x7fffu + ((c.u >> 16) & 1u)) >> 16;
  return (ushort)r;
}

#if HAVE_FP8_CVT
template <bool HI>
__device__ inline f32x2 fp8x2f(unsigned w) {
  return __builtin_amdgcn_cvt_pk_f32_fp8((int)w, HI);
}
template <bool HI>
__device__ inline unsigned fp8pack2(unsigned old, float a, float b) {
  return (unsigned)__builtin_amdgcn_cvt_pk_fp8_f32(a, b, (int)old, HI);
}
#else
__device__ inline float fp8tof_1(unsigned b) {
  unsigned e = (b >> 3) & 15u, m = b & 7u;
  float v;
  if (e == 0) v = (float)m * 0x1p-9f;
  else { union { unsigned u; float f; } c; c.u = ((e + 120u) << 23) | (m << 20); v = c.f; }
  return (b & 0x80u) ? -v : v;
}
template <bool HI>
__device__ inline f32x2 fp8x2f(unsigned w) {
  unsigned sh = HI ? 16 : 0;
  f32x2 r;
  r.x = fp8tof_1((w >> sh) & 0xFFu);
  r.y = fp8tof_1((w >> (sh + 8)) & 0xFFu);
  return r;
}
__device__ inline unsigned f2fp8_1(float f) {
  float af = fabsf(f);
  unsigned s = (f < 0.f) ? 0x80u : 0u;
  if (!(af < 448.f)) return s | 0x7Eu;
  if (af < 0x1p-6f) {
    int m = (int)rintf(af * 512.0f);
    if (m >= 8) return s | 0x08u;
    return s | (unsigned)m;
  }
  int e;
  frexpf(af, &e);
  int E = e - 1;
  int q = (int)rintf(ldexpf(af, 3 - E));
  if (q >= 16) { q = 8; E += 1; if (E > 8) return s | 0x7Eu; }
  return s | ((unsigned)(E + 7) << 3) | ((unsigned)q & 7u);
}
template <bool HI>
__device__ inline unsigned fp8pack2(unsigned old, float a, float b) {
  unsigned pair = f2fp8_1(a) | (f2fp8_1(b) << 8);
  return HI ? ((old & 0x0000FFFFu) | (pair << 16)) : ((old & 0xFFFF0000u) | pair);
}
#endif

// flag detect + zero the pad rows (index N) of xq / gq
__global__ void __launch_bounds__(64) k_detect(const int* __restrict__ ei, int* __restrict__ flag,
                                               unsigned long long* __restrict__ xpad,
                                               unsigned long long* __restrict__ gpad) {
  int t = threadIdx.x;
  int v = ei[2 * t + 1];
  unsigned long long m = __ballot(v != 0);
  if (t == 0) *flag = (m == 0ull) ? 1 : 0;
  if (t < 16) xpad[t] = 0ull;
  if (t < 8)  gpad[t] = 0ull;
}

// x fp32 -> fp8 e4m3 (thread: 8 values, 32B in -> 8B out)
__global__ void __launch_bounds__(256) k_prep_x(const float4* __restrict__ x4, uint2* __restrict__ xq8, int total8) {
  int i = blockIdx.x * 256 + threadIdx.x;
  if (i >= total8) return;
  float4 v0 = x4[2 * i], v1 = x4[2 * i + 1];
  unsigned w0 = fp8pack2<false>(0u, v0.x, v0.y);
  w0 = fp8pack2<true>(w0, v0.z, v0.w);
  unsigned w1 = fp8pack2<false>(0u, v1.x, v1.y);
  w1 = fp8pack2<true>(w1, v1.z, v1.w);
  xq8[i] = make_uint2(w0, w1);
}

// W1[256][128], W2[64][256] -> bf16 MFMA B-fragment order.
__global__ void __launch_bounds__(256) k_prep_w(const float* __restrict__ W1, const float* __restrict__ W2,
                                                ushort* __restrict__ W1f, ushort* __restrict__ W2f) {
  int idx = blockIdx.x * 256 + threadIdx.x;
  if (idx < 32768) {
    int jt = idx >> 11, rem = idx & 2047;
    int kt = rem >> 9, rem2 = rem & 511;
    int l = rem2 >> 3, e = rem2 & 7;
    int k = kt * 32 + (l >> 4) * 8 + e;
    int j = jt * 16 + (l & 15);
    W1f[idx] = f2bf(W1[j * 128 + k]);
  } else {
    int i2 = idx - 32768;
    if (i2 < 16384) {
      int ot = i2 >> 12, rem = i2 & 4095;
      int kt = rem >> 9;
      int l = (rem >> 3) & 63, e = rem & 7;
      int k = kt * 32 + (l >> 4) * 8 + e;
      int o = ot * 16 + (l & 15);
      W2f[i2] = f2bf(W2[o * 256 + k]);
    }
  }
}

__global__ void __launch_bounds__(256) k_bhist(const int* __restrict__ ei, const int* __restrict__ flag,
                                               int* __restrict__ bcnt, int E, int NB) {
  __shared__ int h[128];
  int t = threadIdx.x;
  if (t < 128) h[t] = 0;
  __syncthreads();
  bool f64 = (*flag != 0);
  int stride = gridDim.x * 256;
  for (int e = blockIdx.x * 256 + t; e < E; e += stride) {
    int d;
    if (f64) d = (int)((const long long*)ei)[(size_t)E + e];
    else     d = ei[(size_t)E + e];
    atomicAdd(&h[d >> BSHIFT], 1);
  }
  __syncthreads();
  if (t < NB && h[t]) atomicAdd(&bcnt[t], h[t]);
}

__global__ void __launch_bounds__(128) k_bscan(const int* __restrict__ bcnt, int* __restrict__ bbase,
                                               int* __restrict__ bcur, int* __restrict__ row_ptr,
                                               int NB, int N, int E) {
  __shared__ int s[128];
  int t = threadIdx.x;
  int v = (t < NB) ? bcnt[t] : 0;
  s[t] = v;
  __syncthreads();
  for (int o = 1; o < 128; o <<= 1) {
    int u = (t >= o) ? s[t - o] : 0;
    __syncthreads();
    s[t] += u;
    __syncthreads();
  }
  if (t < NB) {
    int base = s[t] - v;
    bbase[t] = base;
    bcur[t] = base;
  }
  if (t == 0) {
    bbase[NB] = E;
    row_ptr[N] = E;
  }
}

__global__ void __launch_bounds__(256) k_bin(const int* __restrict__ ei, const int* __restrict__ flag,
                                             int* __restrict__ bcur, int* __restrict__ gpair, int E, int NB) {
  __shared__ int hist[128], base[128], segb[128], cur[128], scanb[128];
  __shared__ int ent[TBIN];
  __shared__ int gdx[TBIN];
  int t = threadIdx.x;
  int e0 = blockIdx.x * TBIN;
  int cnt = E - e0; if (cnt > TBIN) cnt = TBIN;
  if (t < 128) hist[t] = 0;
  __syncthreads();
  bool f64 = (*flag != 0);
  int ment[16], mbk[16];
#pragma unroll
  for (int i = 0; i < 16; ++i) {
    int idx = t + i * 256;
    mbk[i] = -1;
    if (idx < cnt) {
      int e = e0 + idx;
      int s, d;
      if (f64) {
        const long long* p = (const long long*)ei;
        s = (int)p[e];
        d = (int)p[(size_t)E + e];
      } else {
        s = ei[e];
        d = ei[(size_t)E + e];
      }
      int b = d >> BSHIFT;
      mbk[i] = b;
      ment[i] = ((d & BMASK) << 17) | s;
      atomicAdd(&hist[b], 1);
    }
  }
  __syncthreads();
  if (t < 128) scanb[t] = hist[t];
  __syncthreads();
  for (int o = 1; o < 128; o <<= 1) {
    int u = 0;
    if (t < 128 && t >= o) u = scanb[t - o];
    __syncthreads();
    if (t < 128) scanb[t] += u;
    __syncthreads();
  }
  if (t < 128) {
    int b0 = scanb[t] - hist[t];
    base[t] = b0;
    cur[t] = b0;
    segb[t] = (t < NB && hist[t] > 0) ? atomicAdd(&bcur[t], hist[t]) : 0;
  }
  __syncthreads();
#pragma unroll
  for (int i = 0; i < 16; ++i) {
    int b = mbk[i];
    if (b >= 0) {
      int pos = atomicAdd(&cur[b], 1);
      ent[pos] = ment[i];
      gdx[pos] = segb[b] + (pos - base[b]);
    }
  }
  __syncthreads();
  for (int i = t; i < cnt; i += 256) gpair[gdx[i]] = ent[i];
}

__global__ void __launch_bounds__(1024) k_bcsr(const int* __restrict__ gpair, const int* __restrict__ bbase,
                                               int* __restrict__ row_ptr, float* __restrict__ inv_deg,
                                               int* __restrict__ csr, int N) {
  __shared__ int hist[1024], pre[1024], cur[1024];
  int b = blockIdx.x, t = threadIdx.x;
  int start = bbase[b], end = bbase[b + 1];
  hist[t] = 0;
  __syncthreads();
  for (int i = start + t; i < end; i += 1024) {
    int e = gpair[i];
    atomicAdd(&hist[e >> 17], 1);
  }
  __syncthreads();
  pre[t] = hist[t];
  __syncthreads();
  for (int o = 1; o < 1024; o <<= 1) {
    int u = (t >= o) ? pre[t - o] : 0;
    __syncthreads();
    pre[t] += u;
    __syncthreads();
  }
  int gbase = start + pre[t] - hist[t];
  int n = (b << BSHIFT) + t;
  if (n < N) {
    row_ptr[n] = gbase;
    inv_deg[n] = 1.0f / (float)(hist[t] > 0 ? hist[t] : 1);
  }
  cur[t] = gbase;
  __syncthreads();
  for (int i = start + t; i < end; i += 1024) {
    int e = gpair[i];
    int pos = atomicAdd(&cur[e >> 17], 1);
    csr[pos] = e & SRCMASK;
  }
}

// agg1: 16-lane group per node, 4 nodes/wave, persistent waves.
// Within a group: 8 lanes/edge x 16B (dwordx4), 2 edges/group-step.
// Pad slots -> zero row N (no inner-loop conditionals).
__global__ void __launch_bounds__(256) k_agg1(const unsigned char* __restrict__ xq, const int* __restrict__ csr,
                                              const int* __restrict__ row_ptr, const float* __restrict__ inv_deg,
                                              ushort* __restrict__ agg1b, int N) {
  const int lane = threadIdx.x & 63;
  const int g = lane >> 4;           // group (node) within wave
  const int g16 = lane & 48;         // group base lane
  const int p = lane & 15;           // staging slot
  const int h = (lane >> 3) & 1;     // edge parity within group
  const int c = lane & 7;            // 16B chunk within row
  const unsigned coff = (unsigned)c * 16u;
  const int shbase = g16 + h;

  const int NQ = (N + 3) >> 2;
  const int tw = gridDim.x * 4;      // total waves (blockDim 256 = 4 waves)
  int quad = (blockIdx.x * 256 + threadIdx.x) >> 6;
  if (quad >= NQ) return;
  int rp = quad * 4 + (lane < 4 ? lane : 4);
  if (rp > N) rp = N;
  int rv = row_ptr[rp];

  for (;;) {
    const int qn = quad + tw;
    int rvn = 0;
    if (qn < NQ) {
      int rpn = qn * 4 + (lane < 4 ? lane : 4);
      if (rpn > N) rpn = N;
      rvn = row_ptr[rpn];
    }
    const int n = quad * 4 + g;
    const int s = __shfl(rv, g);
    const int cnt = __shfl(rv, g + 1) - s;
    int maxc = cnt;
    maxc = max(maxc, __shfl_xor(maxc, 16));
    maxc = max(maxc, __shfl_xor(maxc, 32));

    f32x2 a[8];
#pragma unroll
    for (int i = 0; i < 8; ++i) a[i] = (f32x2)(0.f);

    for (int base = 0; base < maxc; base += 16) {
      int li = base + p;
      int ci = (li < cnt) ? csr[s + li] : N;   // pad -> zero row
#pragma unroll
      for (int u = 0; u < 8; ++u) {
        int idx = __shfl(ci, shbase + 2 * u);
        unsigned off = ((unsigned)idx << 7) + coff;
        const uint4 wv = *(const uint4*)(xq + off);
        a[0] += fp8x2f<false>(wv.x); a[1] += fp8x2f<true>(wv.x);
        a[2] += fp8x2f<false>(wv.y); a[3] += fp8x2f<true>(wv.y);
        a[4] += fp8x2f<false>(wv.z); a[5] += fp8x2f<true>(wv.z);
        a[6] += fp8x2f<false>(wv.w); a[7] += fp8x2f<true>(wv.w);
      }
    }
    // combine the two edge-parity halves (lane bit 3)
#pragma unroll
    for (int i = 0; i < 8; ++i) {
      a[i].x += __shfl_xor(a[i].x, 8);
      a[i].y += __shfl_xor(a[i].y, 8);
    }
    if (n < N) {
      const float inv = inv_deg[n];
      bf16x8 o;
#pragma unroll
      for (int k = 0; k < 4; ++k) {
        f32x2 v0 = a[k], v1 = a[k + 4];
        float vx = h ? v1.x : v0.x;
        float vy = h ? v1.y : v0.y;
        o[2 * k]     = (short)f2bf(vx * inv);
        o[2 * k + 1] = (short)f2bf(vy * inv);
      }
      // lane (c,h) stores features c*16 + h*8 .. +7
      *(bf16x8*)(agg1b + (size_t)n * 128 + c * 16 + h * 8) = o;
    }
    if (qn >= NQ) break;
    quad = qn; rv = rvn;
  }
}

// Fused MFMA MLP: g = relu(agg1 @ W1T + b1) @ W2T, bf16 in, fp8 out, fp32 accum.
__global__ void __launch_bounds__(256) k_mlp(const ushort* __restrict__ agg1b, const bf16x8* __restrict__ w1f,
                                             const float* __restrict__ b1, const bf16x8* __restrict__ w2f,
                                             unsigned char* __restrict__ gq, int N) {
  __shared__ __align__(16) ushort sm[16896];
  ushort* aT = sm;   // phase1: [64][136]
  ushort* hT = sm;   // phase2: [64][264]
  const int t = threadIdx.x;
  const int n0 = blockIdx.x * 64;

#pragma unroll
  for (int i = 0; i < 4; ++i) {
    int idx = i * 256 + t;
    int row = idx >> 4, c8 = idx & 15;
    int rr = n0 + row; if (rr >= N) rr = N - 1;
    bf16x8 v = *(const bf16x8*)(agg1b + (size_t)rr * 128 + c8 * 8);
    *(bf16x8*)(aT + row * 136 + c8 * 8) = v;
  }
  __syncthreads();

  const int w = t >> 6, l = t & 63;
  const int lm = l & 15, lq = l >> 4;

  f32x4 acc[4][4];
#pragma unroll
  for (int mt = 0; mt < 4; ++mt)
#pragma unroll
    for (int nt = 0; nt < 4; ++nt) acc[mt][nt] = (f32x4)(0.f);

#pragma unroll
  for (int kt = 0; kt < 4; ++kt) {
    bf16x8 b[4], a[4];
#pragma unroll
    for (int nt = 0; nt < 4; ++nt)
      b[nt] = w1f[((w * 4 + nt) * 4 + kt) * 64 + l];
#pragma unroll
    for (int mt = 0; mt < 4; ++mt)
      a[mt] = *(const bf16x8*)(aT + (mt * 16 + lm) * 136 + kt * 32 + lq * 8);
#pragma unroll
    for (int mt = 0; mt < 4; ++mt)
#pragma unroll
      for (int nt = 0; nt < 4; ++nt)
        acc[mt][nt] = __builtin_amdgcn_mfma_f32_16x16x32_bf16(a[mt], b[nt], acc[mt][nt], 0, 0, 0);
  }
  __syncthreads();

#pragma unroll
  for (int nt = 0; nt < 4; ++nt) {
    int col = w * 64 + nt * 16 + lm;
    float bb = b1[col];
#pragma unroll
    for (int mt = 0; mt < 4; ++mt)
#pragma unroll
      for (int r = 0; r < 4; ++r) {
        int row = mt * 16 + lq * 4 + r;
        float hv = acc[mt][nt][r] + bb;
        hT[row * 264 + col] = f2bf(fmaxf(hv, 0.f));
      }
  }
  __syncthreads();

  f32x4 acc2[4];
#pragma unroll
  for (int ot = 0; ot < 4; ++ot) acc2[ot] = (f32x4)(0.f);
#pragma unroll
  for (int kt = 0; kt < 8; ++kt) {
    bf16x8 a2 = *(const bf16x8*)(hT + (w * 16 + lm) * 264 + kt * 32 + lq * 8);
#pragma unroll
    for (int ot = 0; ot < 4; ++ot) {
      bf16x8 bf = w2f[(ot * 8 + kt) * 64 + l];
      acc2[ot] = __builtin_amdgcn_mfma_f32_16x16x32_bf16(a2, bf, acc2[ot], 0, 0, 0);
    }
  }
  // write g in fp8 e4m3
#pragma unroll
  for (int ot = 0; ot < 4; ++ot)
#pragma unroll
    for (int r = 0; r < 4; ++r) {
      int row = n0 + w * 16 + lq * 4 + r;
      if (row < N) {
        unsigned pw = fp8pack2<false>(0u, acc2[ot][r], acc2[ot][r]);
        gq[(size_t)row * 64 + ot * 16 + lm] = (unsigned char)(pw & 0xFFu);
      }
    }
}

// agg2 + b2 + log_softmax. 16-lane group per node, 4 nodes/wave, persistent waves.
// Within a group: 4 lanes/edge x 16B (dwordx4), 4 edges/group-step.
// Lane (q2,c): q2 = edge subindex, c = 16B chunk (16 of the 64 features).
__global__ void __launch_bounds__(256) k_agg2(const unsigned char* __restrict__ gq, const int* __restrict__ csr,
                                              const int* __restrict__ row_ptr, const float* __restrict__ inv_deg,
                                              const float* __restrict__ b2, float* __restrict__ out, int N) {
  const int lane = threadIdx.x & 63;
  const int g = lane >> 4;
  const int g16 = lane & 48;
  const int p = lane & 15;
  const int q2 = (lane >> 2) & 3;    // edge subindex
  const int c = lane & 3;            // 16B chunk (features c*16..c*16+15)
  const unsigned coff = (unsigned)c * 16u;
  const int shbase = g16 + q2;

  const int NQ = (N + 3) >> 2;
  const int tw = gridDim.x * 4;
  int quad = (blockIdx.x * 256 + threadIdx.x) >> 6;
  if (quad >= NQ) return;
  int rp = quad * 4 + (lane < 4 ? lane : 4);
  if (rp > N) rp = N;
  int rv = row_ptr[rp];

  // per-lane bias slice b2[c*16 .. +15]
  float4 bv0 = *(const float4*)(b2 + c * 16);
  float4 bv1 = *(const float4*)(b2 + c * 16 + 4);
  float4 bv2 = *(const float4*)(b2 + c * 16 + 8);
  float4 bv3 = *(const float4*)(b2 + c * 16 + 12);

  for (;;) {
    const int qn = quad + tw;
    int rvn = 0;
    if (qn < NQ) {
      int rpn = qn * 4 + (lane < 4 ? lane : 4);
      if (rpn > N) rpn = N;
      rvn = row_ptr[rpn];
    }
    const int n = quad * 4 + g;
    const int s = __shfl(rv, g);
    const int cnt = __shfl(rv, g + 1) - s;
    int maxc = cnt;
    maxc = max(maxc, __shfl_xor(maxc, 16));
    maxc = max(maxc, __shfl_xor(maxc, 32));

    f32x2 a[8];
#pragma unroll
    for (int i = 0; i < 8; ++i) a[i] = (f32x2)(0.f);

    for (int base = 0; base < maxc; base += 16) {
      int li = base + p;
      int ci = (li < cnt) ? csr[s + li] : N;   // pad -> zero row
#pragma unroll
      for (int u = 0; u < 4; ++u) {
        int idx = __shfl(ci, shbase + 4 * u);
        unsigned off = ((unsigned)idx << 6) + coff;
        const uint4 wv = *(const uint4*)(gq + off);
        a[0] += fp8x2f<false>(wv.x); a[1] += fp8x2f<true>(wv.x);
        a[2] += fp8x2f<false>(wv.y); a[3] += fp8x2f<true>(wv.y);
        a[4] += fp8x2f<false>(wv.z); a[5] += fp8x2f<true>(wv.z);
        a[6] += fp8x2f<false>(wv.w); a[7] += fp8x2f<true>(wv.w);
      }
    }
    // reduce across 4 edge-subindex lanes (bits 2,3)
#pragma unroll
    for (int i = 0; i < 8; ++i) {
      a[i].x += __shfl_xor(a[i].x, 4); a[i].y += __shfl_xor(a[i].y, 4);
      a[i].x += __shfl_xor(a[i].x, 8); a[i].y += __shfl_xor(a[i].y, 8);
    }
    const float inv = inv_deg[n < N ? n : 0];
    float v[16];
    v[0]  = a[0].x * inv + bv0.x;  v[1]  = a[0].y * inv + bv0.y;
    v[2]  = a[1].x * inv + bv0.z;  v[3]  = a[1].y * inv + bv0.w;
    v[4]  = a[2].x * inv + bv1.x;  v[5]  = a[2].y * inv + bv1.y;
    v[6]  = a[3].x * inv + bv1.z;  v[7]  = a[3].y * inv + bv1.w;
    v[8]  = a[4].x * inv + bv2.x;  v[9]  = a[4].y * inv + bv2.y;
    v[10] = a[5].x * inv + bv2.z;  v[11] = a[5].y * inv + bv2.w;
    v[12] = a[6].x * inv + bv3.x;  v[13] = a[6].y * inv + bv3.y;
    v[14] = a[7].x * inv + bv3.z;  v[15] = a[7].y * inv + bv3.w;
    float mx = v[0];
#pragma unroll
    for (int j = 1; j < 16; ++j) mx = fmaxf(mx, v[j]);
    mx = fmaxf(mx, __shfl_xor(mx, 1));
    mx = fmaxf(mx, __shfl_xor(mx, 2));
    float se = 0.f;
#pragma unroll
    for (int j = 0; j < 16; ++j) se += expf(v[j] - mx);
    se += __shfl_xor(se, 1);
    se += __shfl_xor(se, 2);
    float lse = mx + logf(se);
    if (n < N && q2 == 0) {
      float* po = out + (size_t)n * 64 + c * 16;
      float4 o0, o1, o2, o3;
      o0.x = v[0] - lse;  o0.y = v[1] - lse;  o0.z = v[2] - lse;  o0.w = v[3] - lse;
      o1.x = v[4] - lse;  o1.y = v[5] - lse;  o1.z = v[6] - lse;  o1.w = v[7] - lse;
      o2.x = v[8] - lse;  o2.y = v[9] - lse;  o2.z = v[10] - lse; o2.w = v[11] - lse;
      o3.x = v[12] - lse; o3.y = v[13] - lse; o3.z = v[14] - lse; o3.w = v[15] - lse;
      *(float4*)(po)      = o0;
      *(float4*)(po + 4)  = o1;
      *(float4*)(po + 8)  = o2;
      *(float4*)(po + 12) = o3;
    }
    if (qn >= NQ) break;
    quad = qn; rv = rvn;
  }
}

extern "C" void kernel_launch(void* const* d_in, const int* in_sizes, int n_in,
                              void* d_out, int out_size, void* d_ws, size_t ws_size,
                              hipStream_t stream) {
  const float* x  = (const float*)d_in[0];
  const int*   ei = (const int*)d_in[1];
  const float* W1 = (const float*)d_in[2];
  const float* b1 = (const float*)d_in[3];
  const float* W2 = (const float*)d_in[4];
  const float* b2 = (const float*)d_in[5];
  float* out = (float*)d_out;
  const int N = in_sizes[0] / 128;  // 100000
  const int E = in_sizes[1] / 2;    // 1600000
  const int NB = (N + BMASK) >> BSHIFT;  // 98

  char* base = (char*)d_ws;
  size_t off = 0;
  auto alloc = [&](size_t bytes) -> char* {
    char* p = base + off;
    off += (bytes + 255) & ~(size_t)255;
    return p;
  };
  int*    flag    = (int*)alloc(4);
  int*    bcnt    = (int*)alloc((size_t)NB * 4);
  int*    bbase   = (int*)alloc((size_t)(NB + 1) * 4);
  int*    bcur    = (int*)alloc((size_t)NB * 4);
  int*    gpair   = (int*)alloc((size_t)E * 4);
  int*    row_ptr = (int*)alloc((size_t)(N + 1) * 4);
  float*  inv_deg = (float*)alloc((size_t)N * 4);
  int*    csr     = (int*)alloc((size_t)E * 4);
  unsigned char* xq = (unsigned char*)alloc((size_t)(N + 1) * 128);  // +1 zero pad row
  ushort* W1f     = (ushort*)alloc((size_t)32768 * 2);
  ushort* W2f     = (ushort*)alloc((size_t)16384 * 2);
  ushort* agg1b   = (ushort*)alloc((size_t)N * 128 * 2);
  unsigned char* gq = (unsigned char*)alloc((size_t)(N + 1) * 64);   // +1 zero pad row
  (void)ws_size; (void)n_in; (void)out_size;

  hipMemsetAsync(bcnt, 0, (size_t)NB * 4, stream);
  k_detect<<<1, 64, 0, stream>>>(ei, flag,
                                 (unsigned long long*)(xq + (size_t)N * 128),
                                 (unsigned long long*)(gq + (size_t)N * 64));
  k_prep_x<<<(N * 16 + 255) / 256, 256, 0, stream>>>((const float4*)x, (uint2*)xq, N * 16);
  k_prep_w<<<192, 256, 0, stream>>>(W1, W2, W1f, W2f);
  k_bhist<<<512, 256, 0, stream>>>(ei, flag, bcnt, E, NB);
  k_bscan<<<1, 128, 0, stream>>>(bcnt, bbase, bcur, row_ptr, NB, N, E);
  k_bin<<<(E + TBIN - 1) / TBIN, 256, 0, stream>>>(ei, flag, bcur, gpair, E, NB);
  k_bcsr<<<NB, 1024, 0, stream>>>(gpair, bbase, row_ptr, inv_deg, csr, N);
  k_agg1<<<2048, 256, 0, stream>>>(xq, csr, row_ptr, inv_deg, agg1b, N);
  k_mlp<<<(N + 63) / 64, 256, 0, stream>>>(agg1b, (const bf16x8*)W1f, b1, (const bf16x8*)W2f, gq, N);
  k_agg2<<<2048, 256, 0, stream>>>(gq, csr, row_ptr, inv_deg, b2, out, N);
}

// Round 7
// 247.973 us; speedup vs baseline: 1.1414x; 1.0979x over previous
//
#include <hip/hip_runtime.h>

// GraphSAGE 2-layer inference.
// detect(+zero pad rows) -> prep (x->fp8, W1/W2 -> MFMA-frag bf16) -> bucketed CSR build
//  -> agg1 = A_mean * x_fp8  (8 lanes/edge x 16B, 8-deep load batch, plain grid)
//  -> fused MLP (bf16 MFMA): g = relu(agg1 @ W1T + b1) @ W2T -> fp8
//  -> agg2 = A_mean * g_fp8 + b2 -> log_softmax (4 lanes/edge x 16B, 8-deep load batch)
// Round-4 lesson: aggs are latency/MLP-bound (equal time at 2x different gather bytes,
// FETCH ~ 8x table = per-XCD compulsory; Little's law needs ~62 lines in flight per CU,
// we sustained ~36). Fix: plain grid (occupancy 67% vs persistent 39%) + batch-issue
// 8 gathers before consuming + csr prefetch between issue and consume.

typedef __attribute__((ext_vector_type(8))) short bf16x8;
typedef __attribute__((ext_vector_type(4))) float f32x4;
typedef __attribute__((ext_vector_type(2))) float f32x2;

#define BSHIFT 10
#define BMASK  1023
#define SRCMASK 0x1FFFF
#define TBIN   4096

#if __has_builtin(__builtin_amdgcn_cvt_pk_f32_fp8) && __has_builtin(__builtin_amdgcn_cvt_pk_fp8_f32)
#define HAVE_FP8_CVT 1
#else
#define HAVE_FP8_CVT 0
#endif

__device__ inline ushort f2bf(float f) {
  union { float f; unsigned u; } c; c.f = f;
  unsigned r = (c.u + 0x7fffu + ((c.u >> 16) & 1u)) >> 16;
  return (ushort)r;
}

#if HAVE_FP8_CVT
template <bool HI>
__device__ inline f32x2 fp8x2f(unsigned w) {
  return __builtin_amdgcn_cvt_pk_f32_fp8((int)w, HI);
}
template <bool HI>
__device__ inline unsigned fp8pack2(unsigned old, float a, float b) {
  return (unsigned)__builtin_amdgcn_cvt_pk_fp8_f32(a, b, (int)old, HI);
}
#else
__device__ inline float fp8tof_1(unsigned b) {
  unsigned e = (b >> 3) & 15u, m = b & 7u;
  float v;
  if (e == 0) v = (float)m * 0x1p-9f;
  else { union { unsigned u; float f; } c; c.u = ((e + 120u) << 23) | (m << 20); v = c.f; }
  return (b & 0x80u) ? -v : v;
}
template <bool HI>
__device__ inline f32x2 fp8x2f(unsigned w) {
  unsigned sh = HI ? 16 : 0;
  f32x2 r;
  r.x = fp8tof_1((w >> sh) & 0xFFu);
  r.y = fp8tof_1((w >> (sh + 8)) & 0xFFu);
  return r;
}
__device__ inline unsigned f2fp8_1(float f) {
  float af = fabsf(f);
  unsigned s = (f < 0.f) ? 0x80u : 0u;
  if (!(af < 448.f)) return s | 0x7Eu;
  if (af < 0x1p-6f) {
    int m = (int)rintf(af * 512.0f);
    if (m >= 8) return s | 0x08u;
    return s | (unsigned)m;
  }
  int e;
  frexpf(af, &e);
  int E = e - 1;
  int q = (int)rintf(ldexpf(af, 3 - E));
  if (q >= 16) { q = 8; E += 1; if (E > 8) return s | 0x7Eu; }
  return s | ((unsigned)(E + 7) << 3) | ((unsigned)q & 7u);
}
template <bool HI>
__device__ inline unsigned fp8pack2(unsigned old, float a, float b) {
  unsigned pair = f2fp8_1(a) | (f2fp8_1(b) << 8);
  return HI ? ((old & 0x0000FFFFu) | (pair << 16)) : ((old & 0xFFFF0000u) | pair);
}
#endif

// flag detect + zero the pad rows (index N) of xq / gq
__global__ void __launch_bounds__(64) k_detect(const int* __restrict__ ei, int* __restrict__ flag,
                                               unsigned long long* __restrict__ xpad,
                                               unsigned long long* __restrict__ gpad) {
  int t = threadIdx.x;
  int v = ei[2 * t + 1];
  unsigned long long m = __ballot(v != 0);
  if (t == 0) *flag = (m == 0ull) ? 1 : 0;
  if (t < 16) xpad[t] = 0ull;
  if (t < 8)  gpad[t] = 0ull;
}

// x fp32 -> fp8 e4m3 (thread: 8 values, 32B in -> 8B out)
__global__ void __launch_bounds__(256) k_prep_x(const float4* __restrict__ x4, uint2* __restrict__ xq8, int total8) {
  int i = blockIdx.x * 256 + threadIdx.x;
  if (i >= total8) return;
  float4 v0 = x4[2 * i], v1 = x4[2 * i + 1];
  unsigned w0 = fp8pack2<false>(0u, v0.x, v0.y);
  w0 = fp8pack2<true>(w0, v0.z, v0.w);
  unsigned w1 = fp8pack2<false>(0u, v1.x, v1.y);
  w1 = fp8pack2<true>(w1, v1.z, v1.w);
  xq8[i] = make_uint2(w0, w1);
}

// W1[256][128], W2[64][256] -> bf16 MFMA B-fragment order.
__global__ void __launch_bounds__(256) k_prep_w(const float* __restrict__ W1, const float* __restrict__ W2,
                                                ushort* __restrict__ W1f, ushort* __restrict__ W2f) {
  int idx = blockIdx.x * 256 + threadIdx.x;
  if (idx < 32768) {
    int jt = idx >> 11, rem = idx & 2047;
    int kt = rem >> 9, rem2 = rem & 511;
    int l = rem2 >> 3, e = rem2 & 7;
    int k = kt * 32 + (l >> 4) * 8 + e;
    int j = jt * 16 + (l & 15);
    W1f[idx] = f2bf(W1[j * 128 + k]);
  } else {
    int i2 = idx - 32768;
    if (i2 < 16384) {
      int ot = i2 >> 12, rem = i2 & 4095;
      int kt = rem >> 9;
      int l = (rem >> 3) & 63, e = rem & 7;
      int k = kt * 32 + (l >> 4) * 8 + e;
      int o = ot * 16 + (l & 15);
      W2f[i2] = f2bf(W2[o * 256 + k]);
    }
  }
}

__global__ void __launch_bounds__(256) k_bhist(const int* __restrict__ ei, const int* __restrict__ flag,
                                               int* __restrict__ bcnt, int E, int NB) {
  __shared__ int h[128];
  int t = threadIdx.x;
  if (t < 128) h[t] = 0;
  __syncthreads();
  bool f64 = (*flag != 0);
  int stride = gridDim.x * 256;
  for (int e = blockIdx.x * 256 + t; e < E; e += stride) {
    int d;
    if (f64) d = (int)((const long long*)ei)[(size_t)E + e];
    else     d = ei[(size_t)E + e];
    atomicAdd(&h[d >> BSHIFT], 1);
  }
  __syncthreads();
  if (t < NB && h[t]) atomicAdd(&bcnt[t], h[t]);
}

__global__ void __launch_bounds__(128) k_bscan(const int* __restrict__ bcnt, int* __restrict__ bbase,
                                               int* __restrict__ bcur, int* __restrict__ row_ptr,
                                               int NB, int N, int E) {
  __shared__ int s[128];
  int t = threadIdx.x;
  int v = (t < NB) ? bcnt[t] : 0;
  s[t] = v;
  __syncthreads();
  for (int o = 1; o < 128; o <<= 1) {
    int u = (t >= o) ? s[t - o] : 0;
    __syncthreads();
    s[t] += u;
    __syncthreads();
  }
  if (t < NB) {
    int base = s[t] - v;
    bbase[t] = base;
    bcur[t] = base;
  }
  if (t == 0) {
    bbase[NB] = E;
    row_ptr[N] = E;
  }
}

__global__ void __launch_bounds__(256) k_bin(const int* __restrict__ ei, const int* __restrict__ flag,
                                             int* __restrict__ bcur, int* __restrict__ gpair, int E, int NB) {
  __shared__ int hist[128], base[128], segb[128], cur[128], scanb[128];
  __shared__ int ent[TBIN];
  __shared__ int gdx[TBIN];
  int t = threadIdx.x;
  int e0 = blockIdx.x * TBIN;
  int cnt = E - e0; if (cnt > TBIN) cnt = TBIN;
  if (t < 128) hist[t] = 0;
  __syncthreads();
  bool f64 = (*flag != 0);
  int ment[16], mbk[16];
#pragma unroll
  for (int i = 0; i < 16; ++i) {
    int idx = t + i * 256;
    mbk[i] = -1;
    if (idx < cnt) {
      int e = e0 + idx;
      int s, d;
      if (f64) {
        const long long* p = (const long long*)ei;
        s = (int)p[e];
        d = (int)p[(size_t)E + e];
      } else {
        s = ei[e];
        d = ei[(size_t)E + e];
      }
      int b = d >> BSHIFT;
      mbk[i] = b;
      ment[i] = ((d & BMASK) << 17) | s;
      atomicAdd(&hist[b], 1);
    }
  }
  __syncthreads();
  if (t < 128) scanb[t] = hist[t];
  __syncthreads();
  for (int o = 1; o < 128; o <<= 1) {
    int u = 0;
    if (t < 128 && t >= o) u = scanb[t - o];
    __syncthreads();
    if (t < 128) scanb[t] += u;
    __syncthreads();
  }
  if (t < 128) {
    int b0 = scanb[t] - hist[t];
    base[t] = b0;
    cur[t] = b0;
    segb[t] = (t < NB && hist[t] > 0) ? atomicAdd(&bcur[t], hist[t]) : 0;
  }
  __syncthreads();
#pragma unroll
  for (int i = 0; i < 16; ++i) {
    int b = mbk[i];
    if (b >= 0) {
      int pos = atomicAdd(&cur[b], 1);
      ent[pos] = ment[i];
      gdx[pos] = segb[b] + (pos - base[b]);
    }
  }
  __syncthreads();
  for (int i = t; i < cnt; i += 256) gpair[gdx[i]] = ent[i];
}

__global__ void __launch_bounds__(1024) k_bcsr(const int* __restrict__ gpair, const int* __restrict__ bbase,
                                               int* __restrict__ row_ptr, float* __restrict__ inv_deg,
                                               int* __restrict__ csr, int N) {
  __shared__ int hist[1024], pre[1024], cur[1024];
  int b = blockIdx.x, t = threadIdx.x;
  int start = bbase[b], end = bbase[b + 1];
  hist[t] = 0;
  __syncthreads();
  for (int i = start + t; i < end; i += 1024) {
    int e = gpair[i];
    atomicAdd(&hist[e >> 17], 1);
  }
  __syncthreads();
  pre[t] = hist[t];
  __syncthreads();
  for (int o = 1; o < 1024; o <<= 1) {
    int u = (t >= o) ? pre[t - o] : 0;
    __syncthreads();
    pre[t] += u;
    __syncthreads();
  }
  int gbase = start + pre[t] - hist[t];
  int n = (b << BSHIFT) + t;
  if (n < N) {
    row_ptr[n] = gbase;
    inv_deg[n] = 1.0f / (float)(hist[t] > 0 ? hist[t] : 1);
  }
  cur[t] = gbase;
  __syncthreads();
  for (int i = start + t; i < end; i += 1024) {
    int e = gpair[i];
    int pos = atomicAdd(&cur[e >> 17], 1);
    csr[pos] = e & SRCMASK;
  }
}

// agg1: 16-lane group per node, 4 nodes/wave, one quad per wave (plain grid).
// 8 lanes/edge x 16B: per 16-edge step, batch-issue ALL 8 dwordx4 gathers, prefetch
// next step's csr between issue and consume. Pad slots -> zero row N.
__global__ void __launch_bounds__(256) k_agg1(const unsigned char* __restrict__ xq, const int* __restrict__ csr,
                                              const int* __restrict__ row_ptr, const float* __restrict__ inv_deg,
                                              ushort* __restrict__ agg1b, int N) {
  const int lane = threadIdx.x & 63;
  const int g = lane >> 4;           // group (node) within wave
  const int g16 = lane & 48;         // group base lane
  const int p = lane & 15;           // staging slot
  const int h = (lane >> 3) & 1;     // edge parity within group
  const int c = lane & 7;            // 16B chunk within row
  const unsigned coff = (unsigned)c * 16u;
  const int shbase = g16 + h;

  const int quad = blockIdx.x * 4 + (threadIdx.x >> 6);
  const int n0 = quad * 4;
  if (n0 >= N) return;
  int rp = n0 + (lane < 4 ? lane : 4);
  if (rp > N) rp = N;
  const int rv = row_ptr[rp];
  const int n = n0 + g;
  const int s = __shfl(rv, g);
  const int cnt = __shfl(rv, g + 1) - s;
  int maxc = cnt;
  maxc = max(maxc, __shfl_xor(maxc, 16));
  maxc = max(maxc, __shfl_xor(maxc, 32));

  f32x2 a[8];
#pragma unroll
  for (int i = 0; i < 8; ++i) a[i] = (f32x2)(0.f);

  int ci = (p < cnt) ? csr[s + p] : N;  // stage step 0
  for (int base = 0; base < maxc; base += 16) {
    // batch-issue 8 independent gathers
    uint4 wv[8];
#pragma unroll
    for (int u = 0; u < 8; ++u) {
      int idx = __shfl(ci, shbase + 2 * u);
      wv[u] = *(const uint4*)(xq + (((unsigned)idx << 7) + coff));
    }
    // prefetch next step's indices while gathers are in flight
    int li = base + 16 + p;
    int cin = (li < cnt) ? csr[s + li] : N;
    // consume
#pragma unroll
    for (int u = 0; u < 8; ++u) {
      a[0] += fp8x2f<false>(wv[u].x); a[1] += fp8x2f<true>(wv[u].x);
      a[2] += fp8x2f<false>(wv[u].y); a[3] += fp8x2f<true>(wv[u].y);
      a[4] += fp8x2f<false>(wv[u].z); a[5] += fp8x2f<true>(wv[u].z);
      a[6] += fp8x2f<false>(wv[u].w); a[7] += fp8x2f<true>(wv[u].w);
    }
    ci = cin;
  }
  // combine the two edge-parity halves (lane bit 3)
#pragma unroll
  for (int i = 0; i < 8; ++i) {
    a[i].x += __shfl_xor(a[i].x, 8);
    a[i].y += __shfl_xor(a[i].y, 8);
  }
  if (n < N) {
    const float inv = inv_deg[n];
    bf16x8 o;
#pragma unroll
    for (int k = 0; k < 4; ++k) {
      f32x2 v0 = a[k], v1 = a[k + 4];
      float vx = h ? v1.x : v0.x;
      float vy = h ? v1.y : v0.y;
      o[2 * k]     = (short)f2bf(vx * inv);
      o[2 * k + 1] = (short)f2bf(vy * inv);
    }
    // lane (c,h) stores features c*16 + h*8 .. +7
    *(bf16x8*)(agg1b + (size_t)n * 128 + c * 16 + h * 8) = o;
  }
}

// Fused MFMA MLP: g = relu(agg1 @ W1T + b1) @ W2T, bf16 in, fp8 out, fp32 accum.
__global__ void __launch_bounds__(256) k_mlp(const ushort* __restrict__ agg1b, const bf16x8* __restrict__ w1f,
                                             const float* __restrict__ b1, const bf16x8* __restrict__ w2f,
                                             unsigned char* __restrict__ gq, int N) {
  __shared__ __align__(16) ushort sm[16896];
  ushort* aT = sm;   // phase1: [64][136]
  ushort* hT = sm;   // phase2: [64][264]
  const int t = threadIdx.x;
  const int n0 = blockIdx.x * 64;

#pragma unroll
  for (int i = 0; i < 4; ++i) {
    int idx = i * 256 + t;
    int row = idx >> 4, c8 = idx & 15;
    int rr = n0 + row; if (rr >= N) rr = N - 1;
    bf16x8 v = *(const bf16x8*)(agg1b + (size_t)rr * 128 + c8 * 8);
    *(bf16x8*)(aT + row * 136 + c8 * 8) = v;
  }
  __syncthreads();

  const int w = t >> 6, l = t & 63;
  const int lm = l & 15, lq = l >> 4;

  f32x4 acc[4][4];
#pragma unroll
  for (int mt = 0; mt < 4; ++mt)
#pragma unroll
    for (int nt = 0; nt < 4; ++nt) acc[mt][nt] = (f32x4)(0.f);

#pragma unroll
  for (int kt = 0; kt < 4; ++kt) {
    bf16x8 b[4], a[4];
#pragma unroll
    for (int nt = 0; nt < 4; ++nt)
      b[nt] = w1f[((w * 4 + nt) * 4 + kt) * 64 + l];
#pragma unroll
    for (int mt = 0; mt < 4; ++mt)
      a[mt] = *(const bf16x8*)(aT + (mt * 16 + lm) * 136 + kt * 32 + lq * 8);
#pragma unroll
    for (int mt = 0; mt < 4; ++mt)
#pragma unroll
      for (int nt = 0; nt < 4; ++nt)
        acc[mt][nt] = __builtin_amdgcn_mfma_f32_16x16x32_bf16(a[mt], b[nt], acc[mt][nt], 0, 0, 0);
  }
  __syncthreads();

#pragma unroll
  for (int nt = 0; nt < 4; ++nt) {
    int col = w * 64 + nt * 16 + lm;
    float bb = b1[col];
#pragma unroll
    for (int mt = 0; mt < 4; ++mt)
#pragma unroll
      for (int r = 0; r < 4; ++r) {
        int row = mt * 16 + lq * 4 + r;
        float hv = acc[mt][nt][r] + bb;
        hT[row * 264 + col] = f2bf(fmaxf(hv, 0.f));
      }
  }
  __syncthreads();

  f32x4 acc2[4];
#pragma unroll
  for (int ot = 0; ot < 4; ++ot) acc2[ot] = (f32x4)(0.f);
#pragma unroll
  for (int kt = 0; kt < 8; ++kt) {
    bf16x8 a2 = *(const bf16x8*)(hT + (w * 16 + lm) * 264 + kt * 32 + lq * 8);
#pragma unroll
    for (int ot = 0; ot < 4; ++ot) {
      bf16x8 bf = w2f[(ot * 8 + kt) * 64 + l];
      acc2[ot] = __builtin_amdgcn_mfma_f32_16x16x32_bf16(a2, bf, acc2[ot], 0, 0, 0);
    }
  }
  // write g in fp8 e4m3
#pragma unroll
  for (int ot = 0; ot < 4; ++ot)
#pragma unroll
    for (int r = 0; r < 4; ++r) {
      int row = n0 + w * 16 + lq * 4 + r;
      if (row < N) {
        unsigned pw = fp8pack2<false>(0u, acc2[ot][r], acc2[ot][r]);
        gq[(size_t)row * 64 + ot * 16 + lm] = (unsigned char)(pw & 0xFFu);
      }
    }
}

// agg2 + b2 + log_softmax. 16-lane group per node, 4 nodes/wave, one quad per wave.
// 4 lanes/edge x 16B: two 16-edge steps fused -> batch-issue 8 dwordx4 gathers,
// csr prefetch between issue and consume. Bias loaded in epilogue only.
__global__ void __launch_bounds__(256) k_agg2(const unsigned char* __restrict__ gq, const int* __restrict__ csr,
                                              const int* __restrict__ row_ptr, const float* __restrict__ inv_deg,
                                              const float* __restrict__ b2, float* __restrict__ out, int N) {
  const int lane = threadIdx.x & 63;
  const int g = lane >> 4;
  const int g16 = lane & 48;
  const int p = lane & 15;
  const int q2 = (lane >> 2) & 3;    // edge subindex
  const int c = lane & 3;            // 16B chunk (features c*16..c*16+15)
  const unsigned coff = (unsigned)c * 16u;
  const int shbase = g16 + q2;

  const int quad = blockIdx.x * 4 + (threadIdx.x >> 6);
  const int n0 = quad * 4;
  if (n0 >= N) return;
  int rp = n0 + (lane < 4 ? lane : 4);
  if (rp > N) rp = N;
  const int rv = row_ptr[rp];
  const int n = n0 + g;
  const int s = __shfl(rv, g);
  const int cnt = __shfl(rv, g + 1) - s;
  int maxc = cnt;
  maxc = max(maxc, __shfl_xor(maxc, 16));
  maxc = max(maxc, __shfl_xor(maxc, 32));

  f32x2 a[8];
#pragma unroll
  for (int i = 0; i < 8; ++i) a[i] = (f32x2)(0.f);

  // stage two 16-edge steps
  int ci0 = (p < cnt) ? csr[s + p] : N;
  int li1 = 16 + p;
  int ci1 = (li1 < cnt) ? csr[s + li1] : N;
  for (int base = 0; base < maxc; base += 32) {
    uint4 wv[8];
#pragma unroll
    for (int u = 0; u < 4; ++u) {
      int idx = __shfl(ci0, shbase + 4 * u);
      wv[u] = *(const uint4*)(gq + (((unsigned)idx << 6) + coff));
    }
#pragma unroll
    for (int u = 0; u < 4; ++u) {
      int idx = __shfl(ci1, shbase + 4 * u);
      wv[4 + u] = *(const uint4*)(gq + (((unsigned)idx << 6) + coff));
    }
    // prefetch next two steps' indices while gathers are in flight
    int li2 = base + 32 + p, li3 = base + 48 + p;
    int cin0 = (li2 < cnt) ? csr[s + li2] : N;
    int cin1 = (li3 < cnt) ? csr[s + li3] : N;
#pragma unroll
    for (int u = 0; u < 8; ++u) {
      a[0] += fp8x2f<false>(wv[u].x); a[1] += fp8x2f<true>(wv[u].x);
      a[2] += fp8x2f<false>(wv[u].y); a[3] += fp8x2f<true>(wv[u].y);
      a[4] += fp8x2f<false>(wv[u].z); a[5] += fp8x2f<true>(wv[u].z);
      a[6] += fp8x2f<false>(wv[u].w); a[7] += fp8x2f<true>(wv[u].w);
    }
    ci0 = cin0; ci1 = cin1;
  }
  // reduce across 4 edge-subindex lanes (bits 2,3)
#pragma unroll
  for (int i = 0; i < 8; ++i) {
    a[i].x += __shfl_xor(a[i].x, 4); a[i].y += __shfl_xor(a[i].y, 4);
    a[i].x += __shfl_xor(a[i].x, 8); a[i].y += __shfl_xor(a[i].y, 8);
  }
  const float inv = inv_deg[n < N ? n : 0];
  // per-lane bias slice b2[c*16 .. +15] (epilogue only -> lower loop VGPR pressure)
  float4 bv0 = *(const float4*)(b2 + c * 16);
  float4 bv1 = *(const float4*)(b2 + c * 16 + 4);
  float4 bv2 = *(const float4*)(b2 + c * 16 + 8);
  float4 bv3 = *(const float4*)(b2 + c * 16 + 12);
  float v[16];
  v[0]  = a[0].x * inv + bv0.x;  v[1]  = a[0].y * inv + bv0.y;
  v[2]  = a[1].x * inv + bv0.z;  v[3]  = a[1].y * inv + bv0.w;
  v[4]  = a[2].x * inv + bv1.x;  v[5]  = a[2].y * inv + bv1.y;
  v[6]  = a[3].x * inv + bv1.z;  v[7]  = a[3].y * inv + bv1.w;
  v[8]  = a[4].x * inv + bv2.x;  v[9]  = a[4].y * inv + bv2.y;
  v[10] = a[5].x * inv + bv2.z;  v[11] = a[5].y * inv + bv2.w;
  v[12] = a[6].x * inv + bv3.x;  v[13] = a[6].y * inv + bv3.y;
  v[14] = a[7].x * inv + bv3.z;  v[15] = a[7].y * inv + bv3.w;
  float mx = v[0];
#pragma unroll
  for (int j = 1; j < 16; ++j) mx = fmaxf(mx, v[j]);
  mx = fmaxf(mx, __shfl_xor(mx, 1));
  mx = fmaxf(mx, __shfl_xor(mx, 2));
  float se = 0.f;
#pragma unroll
  for (int j = 0; j < 16; ++j) se += expf(v[j] - mx);
  se += __shfl_xor(se, 1);
  se += __shfl_xor(se, 2);
  float lse = mx + logf(se);
  if (n < N && q2 == 0) {
    float* po = out + (size_t)n * 64 + c * 16;
    float4 o0, o1, o2, o3;
    o0.x = v[0] - lse;  o0.y = v[1] - lse;  o0.z = v[2] - lse;  o0.w = v[3] - lse;
    o1.x = v[4] - lse;  o1.y = v[5] - lse;  o1.z = v[6] - lse;  o1.w = v[7] - lse;
    o2.x = v[8] - lse;  o2.y = v[9] - lse;  o2.z = v[10] - lse; o2.w = v[11] - lse;
    o3.x = v[12] - lse; o3.y = v[13] - lse; o3.z = v[14] - lse; o3.w = v[15] - lse;
    *(float4*)(po)      = o0;
    *(float4*)(po + 4)  = o1;
    *(float4*)(po + 8)  = o2;
    *(float4*)(po + 12) = o3;
  }
}

extern "C" void kernel_launch(void* const* d_in, const int* in_sizes, int n_in,
                              void* d_out, int out_size, void* d_ws, size_t ws_size,
                              hipStream_t stream) {
  const float* x  = (const float*)d_in[0];
  const int*   ei = (const int*)d_in[1];
  const float* W1 = (const float*)d_in[2];
  const float* b1 = (const float*)d_in[3];
  const float* W2 = (const float*)d_in[4];
  const float* b2 = (const float*)d_in[5];
  float* out = (float*)d_out;
  const int N = in_sizes[0] / 128;  // 100000
  const int E = in_sizes[1] / 2;    // 1600000
  const int NB = (N + BMASK) >> BSHIFT;  // 98

  char* base = (char*)d_ws;
  size_t off = 0;
  auto alloc = [&](size_t bytes) -> char* {
    char* p = base + off;
    off += (bytes + 255) & ~(size_t)255;
    return p;
  };
  int*    flag    = (int*)alloc(4);
  int*    bcnt    = (int*)alloc((size_t)NB * 4);
  int*    bbase   = (int*)alloc((size_t)(NB + 1) * 4);
  int*    bcur    = (int*)alloc((size_t)NB * 4);
  int*    gpair   = (int*)alloc((size_t)E * 4);
  int*    row_ptr = (int*)alloc((size_t)(N + 1) * 4);
  float*  inv_deg = (float*)alloc((size_t)N * 4);
  int*    csr     = (int*)alloc((size_t)E * 4);
  unsigned char* xq = (unsigned char*)alloc((size_t)(N + 1) * 128);  // +1 zero pad row
  ushort* W1f     = (ushort*)alloc((size_t)32768 * 2);
  ushort* W2f     = (ushort*)alloc((size_t)16384 * 2);
  ushort* agg1b   = (ushort*)alloc((size_t)N * 128 * 2);
  unsigned char* gq = (unsigned char*)alloc((size_t)(N + 1) * 64);   // +1 zero pad row
  (void)ws_size; (void)n_in; (void)out_size;

  hipMemsetAsync(bcnt, 0, (size_t)NB * 4, stream);
  k_detect<<<1, 64, 0, stream>>>(ei, flag,
                                 (unsigned long long*)(xq + (size_t)N * 128),
                                 (unsigned long long*)(gq + (size_t)N * 64));
  k_prep_x<<<(N * 16 + 255) / 256, 256, 0, stream>>>((const float4*)x, (uint2*)xq, N * 16);
  k_prep_w<<<192, 256, 0, stream>>>(W1, W2, W1f, W2f);
  k_bhist<<<512, 256, 0, stream>>>(ei, flag, bcnt, E, NB);
  k_bscan<<<1, 128, 0, stream>>>(bcnt, bbase, bcur, row_ptr, NB, N, E);
  k_bin<<<(E + TBIN - 1) / TBIN, 256, 0, stream>>>(ei, flag, bcur, gpair, E, NB);
  k_bcsr<<<NB, 1024, 0, stream>>>(gpair, bbase, row_ptr, inv_deg, csr, N);
  k_agg1<<<(N + 15) / 16, 256, 0, stream>>>(xq, csr, row_ptr, inv_deg, agg1b, N);
  k_mlp<<<(N + 63) / 64, 256, 0, stream>>>(agg1b, (const bf16x8*)W1f, b1, (const bf16x8*)W2f, gq, N);
  k_agg2<<<(N + 15) / 16, 256, 0, stream>>>(gq, csr, row_ptr, inv_deg, b2, out, N);
}

// Round 9
// 245.519 us; speedup vs baseline: 1.1528x; 1.0100x over previous
//
#include <hip/hip_runtime.h>

// GraphSAGE 2-layer inference.
// prep (x->fp8, W1/W2 -> MFMA-frag bf16, +detect+pad-zero) -> bucketed CSR build (256-node buckets)
//  -> agg1 = A_mean * x_fp8  (8 lanes/edge x 16B, 8-deep load batch, plain grid)
//  -> fused MLP (bf16 MFMA): g = relu(agg1 @ W1T + b1) @ W2T -> fp8
//  -> agg2 = A_mean * g_fp8 + b2 -> log_softmax (4 lanes/edge x 16B, 8-deep load batch)
// Round-7 lesson: aggs now ~30us each; the ~185us "rest" is dominated by the CSR chain
// (k_bcsr was 98 blocks x 1024 thr = 38% CU coverage, 10-level scans). Fix: BSHIFT 8
// -> 391 blocks x 256 thr, 8-level scans; fold detect into prep_w.

typedef __attribute__((ext_vector_type(8))) short bf16x8;
typedef __attribute__((ext_vector_type(4))) float f32x4;
typedef __attribute__((ext_vector_type(2))) float f32x2;

#define BSHIFT 8
#define BMASK  255
#define SRCMASK 0x1FFFF
#define TBIN   4096

#if __has_builtin(__builtin_amdgcn_cvt_pk_f32_fp8) && __has_builtin(__builtin_amdgcn_cvt_pk_fp8_f32)
#define HAVE_FP8_CVT 1
#else
#define HAVE_FP8_CVT 0
#endif

__device__ inline ushort f2bf(float f) {
  union { float f; unsigned u; } c; c.f = f;
  unsigned r = (c.u + 0x7fffu + ((c.u >> 16) & 1u)) >> 16;
  return (ushort)r;
}

#if HAVE_FP8_CVT
template <bool HI>
__device__ inline f32x2 fp8x2f(unsigned w) {
  return __builtin_amdgcn_cvt_pk_f32_fp8((int)w, HI);
}
template <bool HI>
__device__ inline unsigned fp8pack2(unsigned old, float a, float b) {
  return (unsigned)__builtin_amdgcn_cvt_pk_fp8_f32(a, b, (int)old, HI);
}
#else
__device__ inline float fp8tof_1(unsigned b) {
  unsigned e = (b >> 3) & 15u, m = b & 7u;
  float v;
  if (e == 0) v = (float)m * 0x1p-9f;
  else { union { unsigned u; float f; } c; c.u = ((e + 120u) << 23) | (m << 20); v = c.f; }
  return (b & 0x80u) ? -v : v;
}
template <bool HI>
__device__ inline f32x2 fp8x2f(unsigned w) {
  unsigned sh = HI ? 16 : 0;
  f32x2 r;
  r.x = fp8tof_1((w >> sh) & 0xFFu);
  r.y = fp8tof_1((w >> (sh + 8)) & 0xFFu);
  return r;
}
__device__ inline unsigned f2fp8_1(float f) {
  float af = fabsf(f);
  unsigned s = (f < 0.f) ? 0x80u : 0u;
  if (!(af < 448.f)) return s | 0x7Eu;
  if (af < 0x1p-6f) {
    int m = (int)rintf(af * 512.0f);
    if (m >= 8) return s | 0x08u;
    return s | (unsigned)m;
  }
  int e;
  frexpf(af, &e);
  int E = e - 1;
  int q = (int)rintf(ldexpf(af, 3 - E));
  if (q >= 16) { q = 8; E += 1; if (E > 8) return s | 0x7Eu; }
  return s | ((unsigned)(E + 7) << 3) | ((unsigned)q & 7u);
}
template <bool HI>
__device__ inline unsigned fp8pack2(unsigned old, float a, float b) {
  unsigned pair = f2fp8_1(a) | (f2fp8_1(b) << 8);
  return HI ? ((old & 0x0000FFFFu) | (pair << 16)) : ((old & 0xFFFF0000u) | pair);
}
#endif

// x fp32 -> fp8 e4m3 (thread: 8 values, 32B in -> 8B out)
__global__ void __launch_bounds__(256) k_prep_x(const float4* __restrict__ x4, uint2* __restrict__ xq8, int total8) {
  int i = blockIdx.x * 256 + threadIdx.x;
  if (i >= total8) return;
  float4 v0 = x4[2 * i], v1 = x4[2 * i + 1];
  unsigned w0 = fp8pack2<false>(0u, v0.x, v0.y);
  w0 = fp8pack2<true>(w0, v0.z, v0.w);
  unsigned w1 = fp8pack2<false>(0u, v1.x, v1.y);
  w1 = fp8pack2<true>(w1, v1.z, v1.w);
  xq8[i] = make_uint2(w0, w1);
}

// W1[256][128], W2[64][256] -> bf16 MFMA B-fragment order.
// Block 0 additionally: int64-detect flag + zero the pad rows (index N) of xq/gq.
__global__ void __launch_bounds__(256) k_prep_w(const float* __restrict__ W1, const float* __restrict__ W2,
                                                ushort* __restrict__ W1f, ushort* __restrict__ W2f,
                                                const int* __restrict__ ei, int* __restrict__ flag,
                                                unsigned long long* __restrict__ xpad,
                                                unsigned long long* __restrict__ gpad) {
  if (blockIdx.x == 0) {
    int t = threadIdx.x;
    if (t < 64) {
      int v = ei[2 * t + 1];
      unsigned long long m = __ballot(v != 0);
      if (t == 0) *flag = (m == 0ull) ? 1 : 0;
      if (t < 16) xpad[t] = 0ull;
      if (t < 8)  gpad[t] = 0ull;
    }
  }
  int idx = blockIdx.x * 256 + threadIdx.x;
  if (idx < 32768) {
    int jt = idx >> 11, rem = idx & 2047;
    int kt = rem >> 9, rem2 = rem & 511;
    int l = rem2 >> 3, e = rem2 & 7;
    int k = kt * 32 + (l >> 4) * 8 + e;
    int j = jt * 16 + (l & 15);
    W1f[idx] = f2bf(W1[j * 128 + k]);
  } else {
    int i2 = idx - 32768;
    if (i2 < 16384) {
      int ot = i2 >> 12, rem = i2 & 4095;
      int kt = rem >> 9;
      int l = (rem >> 3) & 63, e = rem & 7;
      int k = kt * 32 + (l >> 4) * 8 + e;
      int o = ot * 16 + (l & 15);
      W2f[i2] = f2bf(W2[o * 256 + k]);
    }
  }
}

__global__ void __launch_bounds__(256) k_bhist(const int* __restrict__ ei, const int* __restrict__ flag,
                                               int* __restrict__ bcnt, int E, int NB) {
  __shared__ int h[512];
  int t = threadIdx.x;
  h[t] = 0; h[t + 256] = 0;
  __syncthreads();
  bool f64 = (*flag != 0);
  int stride = gridDim.x * 256;
  for (int e = blockIdx.x * 256 + t; e < E; e += stride) {
    int d;
    if (f64) d = (int)((const long long*)ei)[(size_t)E + e];
    else     d = ei[(size_t)E + e];
    atomicAdd(&h[d >> BSHIFT], 1);
  }
  __syncthreads();
  if (t < NB && h[t]) atomicAdd(&bcnt[t], h[t]);
  int t2 = t + 256;
  if (t2 < NB && h[t2]) atomicAdd(&bcnt[t2], h[t2]);
}

__global__ void __launch_bounds__(512) k_bscan(const int* __restrict__ bcnt, int* __restrict__ bbase,
                                               int* __restrict__ bcur, int* __restrict__ row_ptr,
                                               int NB, int N, int E) {
  __shared__ int s[512];
  int t = threadIdx.x;
  int v = (t < NB) ? bcnt[t] : 0;
  s[t] = v;
  __syncthreads();
  for (int o = 1; o < 512; o <<= 1) {
    int u = (t >= o) ? s[t - o] : 0;
    __syncthreads();
    s[t] += u;
    __syncthreads();
  }
  if (t < NB) {
    int base = s[t] - v;
    bbase[t] = base;
    bcur[t] = base;
  }
  if (t == 0) {
    bbase[NB] = E;
    row_ptr[N] = E;
  }
}

__global__ void __launch_bounds__(256) k_bin(const int* __restrict__ ei, const int* __restrict__ flag,
                                             int* __restrict__ bcur, int* __restrict__ gpair, int E, int NB) {
  __shared__ int hist[512], base[512], segb[512], cur[512], scanb[512];
  __shared__ int ent[TBIN];
  __shared__ int gdx[TBIN];
  int t = threadIdx.x;
  int e0 = blockIdx.x * TBIN;
  int cnt = E - e0; if (cnt > TBIN) cnt = TBIN;
  hist[t] = 0; hist[t + 256] = 0;
  __syncthreads();
  bool f64 = (*flag != 0);
  int ment[16], mbk[16];
#pragma unroll
  for (int i = 0; i < 16; ++i) {
    int idx = t + i * 256;
    mbk[i] = -1;
    if (idx < cnt) {
      int e = e0 + idx;
      int s, d;
      if (f64) {
        const long long* p = (const long long*)ei;
        s = (int)p[e];
        d = (int)p[(size_t)E + e];
      } else {
        s = ei[e];
        d = ei[(size_t)E + e];
      }
      int b = d >> BSHIFT;
      mbk[i] = b;
      ment[i] = ((d & BMASK) << 17) | s;
      atomicAdd(&hist[b], 1);
    }
  }
  __syncthreads();
  scanb[t] = hist[t]; scanb[t + 256] = hist[t + 256];
  __syncthreads();
  for (int o = 1; o < 512; o <<= 1) {
    int u0 = (t >= o) ? scanb[t - o] : 0;
    int t2 = t + 256;
    int u1 = (t2 >= o) ? scanb[t2 - o] : 0;
    __syncthreads();
    scanb[t] += u0; scanb[t + 256] += u1;
    __syncthreads();
  }
  {
    int b0 = scanb[t] - hist[t];
    base[t] = b0;
    cur[t] = b0;
    segb[t] = (t < NB && hist[t] > 0) ? atomicAdd(&bcur[t], hist[t]) : 0;
    int t2 = t + 256;
    int b1 = scanb[t2] - hist[t2];
    base[t2] = b1;
    cur[t2] = b1;
    segb[t2] = (t2 < NB && hist[t2] > 0) ? atomicAdd(&bcur[t2], hist[t2]) : 0;
  }
  __syncthreads();
#pragma unroll
  for (int i = 0; i < 16; ++i) {
    int b = mbk[i];
    if (b >= 0) {
      int pos = atomicAdd(&cur[b], 1);
      ent[pos] = ment[i];
      gdx[pos] = segb[b] + (pos - base[b]);
    }
  }
  __syncthreads();
  for (int i = t; i < cnt; i += 256) gpair[gdx[i]] = ent[i];
}

// One 256-thread block per 256-node bucket (NB=391 blocks -> better CU coverage than
// the old 98x1024 shape; scans are 8-level instead of 10-level).
__global__ void __launch_bounds__(256) k_bcsr(const int* __restrict__ gpair, const int* __restrict__ bbase,
                                              int* __restrict__ row_ptr, float* __restrict__ inv_deg,
                                              int* __restrict__ csr, int N) {
  __shared__ int hist[256], pre[256], cur[256];
  int b = blockIdx.x, t = threadIdx.x;
  int start = bbase[b], end = bbase[b + 1];
  hist[t] = 0;
  __syncthreads();
  for (int i = start + t; i < end; i += 256) {
    int e = gpair[i];
    atomicAdd(&hist[e >> 17], 1);
  }
  __syncthreads();
  pre[t] = hist[t];
  __syncthreads();
  for (int o = 1; o < 256; o <<= 1) {
    int u = (t >= o) ? pre[t - o] : 0;
    __syncthreads();
    pre[t] += u;
    __syncthreads();
  }
  int gbase = start + pre[t] - hist[t];
  int n = (b << BSHIFT) + t;
  if (n < N) {
    row_ptr[n] = gbase;
    inv_deg[n] = 1.0f / (float)(hist[t] > 0 ? hist[t] : 1);
  }
  cur[t] = gbase;
  __syncthreads();
  for (int i = start + t; i < end; i += 256) {
    int e = gpair[i];
    int pos = atomicAdd(&cur[e >> 17], 1);
    csr[pos] = e & SRCMASK;
  }
}

// agg1: 16-lane group per node, 4 nodes/wave, one quad per wave (plain grid).
// 8 lanes/edge x 16B: per 16-edge step, batch-issue ALL 8 dwordx4 gathers, prefetch
// next step's csr between issue and consume. Pad slots -> zero row N.
__global__ void __launch_bounds__(256) k_agg1(const unsigned char* __restrict__ xq, const int* __restrict__ csr,
                                              const int* __restrict__ row_ptr, const float* __restrict__ inv_deg,
                                              ushort* __restrict__ agg1b, int N) {
  const int lane = threadIdx.x & 63;
  const int g = lane >> 4;           // group (node) within wave
  const int g16 = lane & 48;         // group base lane
  const int p = lane & 15;           // staging slot
  const int h = (lane >> 3) & 1;     // edge parity within group
  const int c = lane & 7;            // 16B chunk within row
  const unsigned coff = (unsigned)c * 16u;
  const int shbase = g16 + h;

  const int quad = blockIdx.x * 4 + (threadIdx.x >> 6);
  const int n0 = quad * 4;
  if (n0 >= N) return;
  int rp = n0 + (lane < 4 ? lane : 4);
  if (rp > N) rp = N;
  const int rv = row_ptr[rp];
  const int n = n0 + g;
  const int s = __shfl(rv, g);
  const int cnt = __shfl(rv, g + 1) - s;
  int maxc = cnt;
  maxc = max(maxc, __shfl_xor(maxc, 16));
  maxc = max(maxc, __shfl_xor(maxc, 32));

  f32x2 a[8];
#pragma unroll
  for (int i = 0; i < 8; ++i) a[i] = (f32x2)(0.f);

  int ci = (p < cnt) ? csr[s + p] : N;  // stage step 0
  for (int base = 0; base < maxc; base += 16) {
    // batch-issue 8 independent gathers
    uint4 wv[8];
#pragma unroll
    for (int u = 0; u < 8; ++u) {
      int idx = __shfl(ci, shbase + 2 * u);
      wv[u] = *(const uint4*)(xq + (((unsigned)idx << 7) + coff));
    }
    // prefetch next step's indices while gathers are in flight
    int li = base + 16 + p;
    int cin = (li < cnt) ? csr[s + li] : N;
    // consume
#pragma unroll
    for (int u = 0; u < 8; ++u) {
      a[0] += fp8x2f<false>(wv[u].x); a[1] += fp8x2f<true>(wv[u].x);
      a[2] += fp8x2f<false>(wv[u].y); a[3] += fp8x2f<true>(wv[u].y);
      a[4] += fp8x2f<false>(wv[u].z); a[5] += fp8x2f<true>(wv[u].z);
      a[6] += fp8x2f<false>(wv[u].w); a[7] += fp8x2f<true>(wv[u].w);
    }
    ci = cin;
  }
  // combine the two edge-parity halves (lane bit 3)
#pragma unroll
  for (int i = 0; i < 8; ++i) {
    a[i].x += __shfl_xor(a[i].x, 8);
    a[i].y += __shfl_xor(a[i].y, 8);
  }
  if (n < N) {
    const float inv = inv_deg[n];
    bf16x8 o;
#pragma unroll
    for (int k = 0; k < 4; ++k) {
      f32x2 v0 = a[k], v1 = a[k + 4];
      float vx = h ? v1.x : v0.x;
      float vy = h ? v1.y : v0.y;
      o[2 * k]     = (short)f2bf(vx * inv);
      o[2 * k + 1] = (short)f2bf(vy * inv);
    }
    // lane (c,h) stores features c*16 + h*8 .. +7
    *(bf16x8*)(agg1b + (size_t)n * 128 + c * 16 + h * 8) = o;
  }
}

// Fused MFMA MLP: g = relu(agg1 @ W1T + b1) @ W2T, bf16 in, fp8 out, fp32 accum.
__global__ void __launch_bounds__(256) k_mlp(const ushort* __restrict__ agg1b, const bf16x8* __restrict__ w1f,
                                             const float* __restrict__ b1, const bf16x8* __restrict__ w2f,
                                             unsigned char* __restrict__ gq, int N) {
  __shared__ __align__(16) ushort sm[16896];
  ushort* aT = sm;   // phase1: [64][136]
  ushort* hT = sm;   // phase2: [64][264]
  const int t = threadIdx.x;
  const int n0 = blockIdx.x * 64;

#pragma unroll
  for (int i = 0; i < 4; ++i) {
    int idx = i * 256 + t;
    int row = idx >> 4, c8 = idx & 15;
    int rr = n0 + row; if (rr >= N) rr = N - 1;
    bf16x8 v = *(const bf16x8*)(agg1b + (size_t)rr * 128 + c8 * 8);
    *(bf16x8*)(aT + row * 136 + c8 * 8) = v;
  }
  __syncthreads();

  const int w = t >> 6, l = t & 63;
  const int lm = l & 15, lq = l >> 4;

  f32x4 acc[4][4];
#pragma unroll
  for (int mt = 0; mt < 4; ++mt)
#pragma unroll
    for (int nt = 0; nt < 4; ++nt) acc[mt][nt] = (f32x4)(0.f);

#pragma unroll
  for (int kt = 0; kt < 4; ++kt) {
    bf16x8 b[4], a[4];
#pragma unroll
    for (int nt = 0; nt < 4; ++nt)
      b[nt] = w1f[((w * 4 + nt) * 4 + kt) * 64 + l];
#pragma unroll
    for (int mt = 0; mt < 4; ++mt)
      a[mt] = *(const bf16x8*)(aT + (mt * 16 + lm) * 136 + kt * 32 + lq * 8);
#pragma unroll
    for (int mt = 0; mt < 4; ++mt)
#pragma unroll
      for (int nt = 0; nt < 4; ++nt)
        acc[mt][nt] = __builtin_amdgcn_mfma_f32_16x16x32_bf16(a[mt], b[nt], acc[mt][nt], 0, 0, 0);
  }
  __syncthreads();

#pragma unroll
  for (int nt = 0; nt < 4; ++nt) {
    int col = w * 64 + nt * 16 + lm;
    float bb = b1[col];
#pragma unroll
    for (int mt = 0; mt < 4; ++mt)
#pragma unroll
      for (int r = 0; r < 4; ++r) {
        int row = mt * 16 + lq * 4 + r;
        float hv = acc[mt][nt][r] + bb;
        hT[row * 264 + col] = f2bf(fmaxf(hv, 0.f));
      }
  }
  __syncthreads();

  f32x4 acc2[4];
#pragma unroll
  for (int ot = 0; ot < 4; ++ot) acc2[ot] = (f32x4)(0.f);
#pragma unroll
  for (int kt = 0; kt < 8; ++kt) {
    bf16x8 a2 = *(const bf16x8*)(hT + (w * 16 + lm) * 264 + kt * 32 + lq * 8);
#pragma unroll
    for (int ot = 0; ot < 4; ++ot) {
      bf16x8 bf = w2f[(ot * 8 + kt) * 64 + l];
      acc2[ot] = __builtin_amdgcn_mfma_f32_16x16x32_bf16(a2, bf, acc2[ot], 0, 0, 0);
    }
  }
  // write g in fp8 e4m3
#pragma unroll
  for (int ot = 0; ot < 4; ++ot)
#pragma unroll
    for (int r = 0; r < 4; ++r) {
      int row = n0 + w * 16 + lq * 4 + r;
      if (row < N) {
        unsigned pw = fp8pack2<false>(0u, acc2[ot][r], acc2[ot][r]);
        gq[(size_t)row * 64 + ot * 16 + lm] = (unsigned char)(pw & 0xFFu);
      }
    }
}

// agg2 + b2 + log_softmax. 16-lane group per node, 4 nodes/wave, one quad per wave.
// 4 lanes/edge x 16B: two 16-edge steps fused -> batch-issue 8 dwordx4 gathers,
// csr prefetch between issue and consume. Bias loaded in epilogue only.
__global__ void __launch_bounds__(256) k_agg2(const unsigned char* __restrict__ gq, const int* __restrict__ csr,
                                              const int* __restrict__ row_ptr, const float* __restrict__ inv_deg,
                                              const float* __restrict__ b2, float* __restrict__ out, int N) {
  const int lane = threadIdx.x & 63;
  const int g = lane >> 4;
  const int g16 = lane & 48;
  const int p = lane & 15;
  const int q2 = (lane >> 2) & 3;    // edge subindex
  const int c = lane & 3;            // 16B chunk (features c*16..c*16+15)
  const unsigned coff = (unsigned)c * 16u;
  const int shbase = g16 + q2;

  const int quad = blockIdx.x * 4 + (threadIdx.x >> 6);
  const int n0 = quad * 4;
  if (n0 >= N) return;
  int rp = n0 + (lane < 4 ? lane : 4);
  if (rp > N) rp = N;
  const int rv = row_ptr[rp];
  const int n = n0 + g;
  const int s = __shfl(rv, g);
  const int cnt = __shfl(rv, g + 1) - s;
  int maxc = cnt;
  maxc = max(maxc, __shfl_xor(maxc, 16));
  maxc = max(maxc, __shfl_xor(maxc, 32));

  f32x2 a[8];
#pragma unroll
  for (int i = 0; i < 8; ++i) a[i] = (f32x2)(0.f);

  // stage two 16-edge steps
  int ci0 = (p < cnt) ? csr[s + p] : N;
  int li1 = 16 + p;
  int ci1 = (li1 < cnt) ? csr[s + li1] : N;
  for (int base = 0; base < maxc; base += 32) {
    uint4 wv[8];
#pragma unroll
    for (int u = 0; u < 4; ++u) {
      int idx = __shfl(ci0, shbase + 4 * u);
      wv[u] = *(const uint4*)(gq + (((unsigned)idx << 6) + coff));
    }
#pragma unroll
    for (int u = 0; u < 4; ++u) {
      int idx = __shfl(ci1, shbase + 4 * u);
      wv[4 + u] = *(const uint4*)(gq + (((unsigned)idx << 6) + coff));
    }
    // prefetch next two steps' indices while gathers are in flight
    int li2 = base + 32 + p, li3 = base + 48 + p;
    int cin0 = (li2 < cnt) ? csr[s + li2] : N;
    int cin1 = (li3 < cnt) ? csr[s + li3] : N;
#pragma unroll
    for (int u = 0; u < 8; ++u) {
      a[0] += fp8x2f<false>(wv[u].x); a[1] += fp8x2f<true>(wv[u].x);
      a[2] += fp8x2f<false>(wv[u].y); a[3] += fp8x2f<true>(wv[u].y);
      a[4] += fp8x2f<false>(wv[u].z); a[5] += fp8x2f<true>(wv[u].z);
      a[6] += fp8x2f<false>(wv[u].w); a[7] += fp8x2f<true>(wv[u].w);
    }
    ci0 = cin0; ci1 = cin1;
  }
  // reduce across 4 edge-subindex lanes (bits 2,3)
#pragma unroll
  for (int i = 0; i < 8; ++i) {
    a[i].x += __shfl_xor(a[i].x, 4); a[i].y += __shfl_xor(a[i].y, 4);
    a[i].x += __shfl_xor(a[i].x, 8); a[i].y += __shfl_xor(a[i].y, 8);
  }
  const float inv = inv_deg[n < N ? n : 0];
  // per-lane bias slice b2[c*16 .. +15] (epilogue only -> lower loop VGPR pressure)
  float4 bv0 = *(const float4*)(b2 + c * 16);
  float4 bv1 = *(const float4*)(b2 + c * 16 + 4);
  float4 bv2 = *(const float4*)(b2 + c * 16 + 8);
  float4 bv3 = *(const float4*)(b2 + c * 16 + 12);
  float v[16];
  v[0]  = a[0].x * inv + bv0.x;  v[1]  = a[0].y * inv + bv0.y;
  v[2]  = a[1].x * inv + bv0.z;  v[3]  = a[1].y * inv + bv0.w;
  v[4]  = a[2].x * inv + bv1.x;  v[5]  = a[2].y * inv + bv1.y;
  v[6]  = a[3].x * inv + bv1.z;  v[7]  = a[3].y * inv + bv1.w;
  v[8]  = a[4].x * inv + bv2.x;  v[9]  = a[4].y * inv + bv2.y;
  v[10] = a[5].x * inv + bv2.z;  v[11] = a[5].y * inv + bv2.w;
  v[12] = a[6].x * inv + bv3.x;  v[13] = a[6].y * inv + bv3.y;
  v[14] = a[7].x * inv + bv3.z;  v[15] = a[7].y * inv + bv3.w;
  float mx = v[0];
#pragma unroll
  for (int j = 1; j < 16; ++j) mx = fmaxf(mx, v[j]);
  mx = fmaxf(mx, __shfl_xor(mx, 1));
  mx = fmaxf(mx, __shfl_xor(mx, 2));
  float se = 0.f;
#pragma unroll
  for (int j = 0; j < 16; ++j) se += expf(v[j] - mx);
  se += __shfl_xor(se, 1);
  se += __shfl_xor(se, 2);
  float lse = mx + logf(se);
  if (n < N && q2 == 0) {
    float* po = out + (size_t)n * 64 + c * 16;
    float4 o0, o1, o2, o3;
    o0.x = v[0] - lse;  o0.y = v[1] - lse;  o0.z = v[2] - lse;  o0.w = v[3] - lse;
    o1.x = v[4] - lse;  o1.y = v[5] - lse;  o1.z = v[6] - lse;  o1.w = v[7] - lse;
    o2.x = v[8] - lse;  o2.y = v[9] - lse;  o2.z = v[10] - lse; o2.w = v[11] - lse;
    o3.x = v[12] - lse; o3.y = v[13] - lse; o3.z = v[14] - lse; o3.w = v[15] - lse;
    *(float4*)(po)      = o0;
    *(float4*)(po + 4)  = o1;
    *(float4*)(po + 8)  = o2;
    *(float4*)(po + 12) = o3;
  }
}

extern "C" void kernel_launch(void* const* d_in, const int* in_sizes, int n_in,
                              void* d_out, int out_size, void* d_ws, size_t ws_size,
                              hipStream_t stream) {
  const float* x  = (const float*)d_in[0];
  const int*   ei = (const int*)d_in[1];
  const float* W1 = (const float*)d_in[2];
  const float* b1 = (const float*)d_in[3];
  const float* W2 = (const float*)d_in[4];
  const float* b2 = (const float*)d_in[5];
  float* out = (float*)d_out;
  const int N = in_sizes[0] / 128;  // 100000
  const int E = in_sizes[1] / 2;    // 1600000
  const int NB = (N + BMASK) >> BSHIFT;  // 391

  char* base = (char*)d_ws;
  size_t off = 0;
  auto alloc = [&](size_t bytes) -> char* {
    char* p = base + off;
    off += (bytes + 255) & ~(size_t)255;
    return p;
  };
  int*    flag    = (int*)alloc(4);
  int*    bcnt    = (int*)alloc((size_t)NB * 4);
  int*    bbase   = (int*)alloc((size_t)(NB + 1) * 4);
  int*    bcur    = (int*)alloc((size_t)NB * 4);
  int*    gpair   = (int*)alloc((size_t)E * 4);
  int*    row_ptr = (int*)alloc((size_t)(N + 1) * 4);
  float*  inv_deg = (float*)alloc((size_t)N * 4);
  int*    csr     = (int*)alloc((size_t)E * 4);
  unsigned char* xq = (unsigned char*)alloc((size_t)(N + 1) * 128);  // +1 zero pad row
  ushort* W1f     = (ushort*)alloc((size_t)32768 * 2);
  ushort* W2f     = (ushort*)alloc((size_t)16384 * 2);
  ushort* agg1b   = (ushort*)alloc((size_t)N * 128 * 2);
  unsigned char* gq = (unsigned char*)alloc((size_t)(N + 1) * 64);   // +1 zero pad row
  (void)ws_size; (void)n_in; (void)out_size;

  hipMemsetAsync(bcnt, 0, (size_t)NB * 4, stream);
  k_prep_x<<<(N * 16 + 255) / 256, 256, 0, stream>>>((const float4*)x, (uint2*)xq, N * 16);
  k_prep_w<<<192, 256, 0, stream>>>(W1, W2, W1f, W2f, ei, flag,
                                    (unsigned long long*)(xq + (size_t)N * 128),
                                    (unsigned long long*)(gq + (size_t)N * 64));
  k_bhist<<<512, 256, 0, stream>>>(ei, flag, bcnt, E, NB);
  k_bscan<<<1, 512, 0, stream>>>(bcnt, bbase, bcur, row_ptr, NB, N, E);
  k_bin<<<(E + TBIN - 1) / TBIN, 256, 0, stream>>>(ei, flag, bcur, gpair, E, NB);
  k_bcsr<<<NB, 256, 0, stream>>>(gpair, bbase, row_ptr, inv_deg, csr, N);
  k_agg1<<<(N + 15) / 16, 256, 0, stream>>>(xq, csr, row_ptr, inv_deg, agg1b, N);
  k_mlp<<<(N + 63) / 64, 256, 0, stream>>>(agg1b, (const bf16x8*)W1f, b1, (const bf16x8*)W2f, gq, N);
  k_agg2<<<(N + 15) / 16, 256, 0, stream>>>(gq, csr, row_ptr, inv_deg, b2, out, N);
}